// Round 1
// baseline (1280.089 us; speedup 1.0000x reference)
//
#include <hip/hip_runtime.h>
#include <hip/hip_bf16.h>
#include <math.h>

#define NN 10000      // nodes
#define NE 160000     // edges
#define NF 9          // atom features
#define VOCAB 128
#define D 128
#define NH 4          // heads
#define C 128
#define HC 512        // NH*C
#define NCLS 10

// ---- order-preserving float<->uint encoding for atomicMax on floats ----
__device__ __forceinline__ unsigned fenc(float f) {
    unsigned u = __float_as_uint(f);
    return (u & 0x80000000u) ? ~u : (u | 0x80000000u);
}
__device__ __forceinline__ float fdec(unsigned u) {
    return (u & 0x80000000u) ? __uint_as_float(u & 0x7FFFFFFFu)
                             : __uint_as_float(~u);
}

// ---- K0: atom encoder: x[n,d] = sum_f emb[f, feat[n,f], d] ----
__global__ __launch_bounds__(128)
void atom_encoder(const int* __restrict__ feats, const float* __restrict__ emb,
                  float* __restrict__ x) {
    int n = blockIdx.x;
    int d = threadIdx.x;
    __shared__ int f[NF];
    if (threadIdx.x < NF) f[threadIdx.x] = feats[n * NF + threadIdx.x];
    __syncthreads();
    float acc = 0.f;
#pragma unroll
    for (int i = 0; i < NF; ++i)
        acc += emb[(i * VOCAB + f[i]) * D + d];
    x[n * D + d] = acc;
}

// ---- K1: fp32 GEMM h = x @ W_l  ([NN,128] @ [128,512]) ----
#define BM 64
#define BN 64
#define BK 32
__global__ __launch_bounds__(256)
void gemm64(const float* __restrict__ X, const float* __restrict__ Wm,
            float* __restrict__ Hh) {
    __shared__ float sA[BK][BM];
    __shared__ float sB[BK][BN];
    int t = threadIdx.x;
    int bm = blockIdx.x * BM;
    int bn = blockIdx.y * BN;
    int tr = t >> 4, tc = t & 15;
    float acc[4][4] = {};
    for (int kk = 0; kk < D; kk += BK) {
#pragma unroll
        for (int i = 0; i < 2; ++i) {           // A: 64x32, transposed store
            int j = t + i * 256;
            int row = j >> 3, kc = (j & 7) * 4;
            float4 v = make_float4(0.f, 0.f, 0.f, 0.f);
            int gr = bm + row;
            if (gr < NN) v = *(const float4*)(X + gr * D + kk + kc);
            sA[kc + 0][row] = v.x; sA[kc + 1][row] = v.y;
            sA[kc + 2][row] = v.z; sA[kc + 3][row] = v.w;
        }
#pragma unroll
        for (int i = 0; i < 2; ++i) {           // B: 32x64, direct float4
            int j = t + i * 256;
            int kr = j >> 4, cc = (j & 15) * 4;
            *(float4*)&sB[kr][cc] = *(const float4*)(Wm + (kk + kr) * HC + bn + cc);
        }
        __syncthreads();
#pragma unroll
        for (int k = 0; k < BK; ++k) {
            float4 a = *(const float4*)&sA[k][tr * 4];
            float4 b = *(const float4*)&sB[k][tc * 4];
            float av[4] = {a.x, a.y, a.z, a.w};
            float bv[4] = {b.x, b.y, b.z, b.w};
#pragma unroll
            for (int mi = 0; mi < 4; ++mi)
#pragma unroll
                for (int ni = 0; ni < 4; ++ni)
                    acc[mi][ni] = fmaf(av[mi], bv[ni], acc[mi][ni]);
        }
        __syncthreads();
    }
#pragma unroll
    for (int mi = 0; mi < 4; ++mi) {
        int gr = bm + tr * 4 + mi;
        if (gr < NN)
            *(float4*)(Hh + gr * HC + bn + tc * 4) =
                make_float4(acc[mi][0], acc[mi][1], acc[mi][2], acc[mi][3]);
    }
}

// ---- K2: per-node attention coefficients (src & dst), 1 wave per node ----
__global__ __launch_bounds__(64)
void alphas(const float* __restrict__ Hh, const float* __restrict__ as_,
            const float* __restrict__ ad_, float* __restrict__ alpha_src,
            float* __restrict__ alpha_dst) {
    int n = blockIdx.x;
    int lane = threadIdx.x;
    const float* hn = Hh + n * HC;
#pragma unroll
    for (int h = 0; h < NH; ++h) {
        float x0 = hn[h * C + lane], x1 = hn[h * C + lane + 64];
        float s = x0 * as_[h * C + lane] + x1 * as_[h * C + lane + 64];
        float d = x0 * ad_[h * C + lane] + x1 * ad_[h * C + lane + 64];
#pragma unroll
        for (int off = 32; off; off >>= 1) {
            s += __shfl_down(s, off);
            d += __shfl_down(d, off);
        }
        if (lane == 0) { alpha_src[n * NH + h] = s; alpha_dst[n * NH + h] = d; }
    }
}

// ---- K3a: init segment-max buffer to enc(-inf) ----
__global__ void init_menc(unsigned* __restrict__ m) {
    int i = blockIdx.x * 256 + threadIdx.x;
    if (i < NN * NH) m[i] = 0x007FFFFFu;   // fenc(-inf)
}

// ---- K3: edge logits + LeakyReLU + atomic segment max ----
__global__ __launch_bounds__(256)
void edge_scores(const int* __restrict__ src, const int* __restrict__ dst,
                 const float* __restrict__ asr, const float* __restrict__ adr,
                 float* __restrict__ ebuf, unsigned* __restrict__ menc) {
    int e = blockIdx.x * 256 + threadIdx.x;
    if (e >= NE) return;
    int s = src[e], d = dst[e];
    float4 a = *(const float4*)(asr + s * 4);
    float4 b = *(const float4*)(adr + d * 4);
    float v[4] = {a.x + b.x, a.y + b.y, a.z + b.z, a.w + b.w};
#pragma unroll
    for (int h = 0; h < 4; ++h) {
        float x = v[h];
        x = x >= 0.f ? x : 0.2f * x;
        v[h] = x;
        atomicMax(menc + d * 4 + h, fenc(x));
    }
    *(float4*)(ebuf + e * 4) = make_float4(v[0], v[1], v[2], v[3]);
}

// ---- K4: ex = exp(e - m[dst]); segment sum ----
__global__ __launch_bounds__(256)
void edge_exp(const int* __restrict__ dst, float* __restrict__ ebuf,
              const unsigned* __restrict__ menc, float* __restrict__ ssum) {
    int e = blockIdx.x * 256 + threadIdx.x;
    if (e >= NE) return;
    int d = dst[e];
    float4 v = *(const float4*)(ebuf + e * 4);
    uint4 mu = *(const uint4*)(menc + d * 4);
    float ex0 = expf(v.x - fdec(mu.x));
    float ex1 = expf(v.y - fdec(mu.y));
    float ex2 = expf(v.z - fdec(mu.z));
    float ex3 = expf(v.w - fdec(mu.w));
    atomicAdd(ssum + d * 4 + 0, ex0);
    atomicAdd(ssum + d * 4 + 1, ex1);
    atomicAdd(ssum + d * 4 + 2, ex2);
    atomicAdd(ssum + d * 4 + 3, ex3);
    *(float4*)(ebuf + e * 4) = make_float4(ex0, ex1, ex2, ex3);
}

// ---- K5: alpha_w = ex / (s[dst]+1e-16) * (1/NH)  (in place) ----
__global__ __launch_bounds__(256)
void edge_alpha(const int* __restrict__ dst, float* __restrict__ ebuf,
                const float* __restrict__ ssum) {
    int e = blockIdx.x * 256 + threadIdx.x;
    if (e >= NE) return;
    int d = dst[e];
    float4 ex = *(const float4*)(ebuf + e * 4);
    float4 sv = *(const float4*)(ssum + d * 4);
    ex.x = ex.x / (sv.x + 1e-16f) * 0.25f;
    ex.y = ex.y / (sv.y + 1e-16f) * 0.25f;
    ex.z = ex.z / (sv.z + 1e-16f) * 0.25f;
    ex.w = ex.w / (sv.w + 1e-16f) * 0.25f;
    *(float4*)(ebuf + e * 4) = ex;
}

// ---- K6: edge aggregation, head-mean folded in; 32 threads/edge ----
__global__ __launch_bounds__(256)
void aggregate(const int* __restrict__ src, const int* __restrict__ dst,
               const float* __restrict__ aw, const float* __restrict__ Hh,
               float* __restrict__ outx) {
    int tid = blockIdx.x * 256 + threadIdx.x;
    int e = tid >> 5;
    if (e >= NE) return;
    int q = tid & 31;
    int c = q * 4;
    float4 w = *(const float4*)(aw + e * 4);
    int s = src[e], d = dst[e];
    const float* hs = Hh + s * HC;
    float4 h0 = *(const float4*)(hs + 0 * C + c);
    float4 h1 = *(const float4*)(hs + 1 * C + c);
    float4 h2 = *(const float4*)(hs + 2 * C + c);
    float4 h3 = *(const float4*)(hs + 3 * C + c);
    float r0 = w.x * h0.x + w.y * h1.x + w.z * h2.x + w.w * h3.x;
    float r1 = w.x * h0.y + w.y * h1.y + w.z * h2.y + w.w * h3.y;
    float r2 = w.x * h0.z + w.y * h1.z + w.z * h2.z + w.w * h3.z;
    float r3 = w.x * h0.w + w.y * h1.w + w.z * h2.w + w.w * h3.w;
    float* o = outx + d * D + c;
    atomicAdd(o + 0, r0);
    atomicAdd(o + 1, r1);
    atomicAdd(o + 2, r2);
    atomicAdd(o + 3, r3);
}

// ---- K7: x = out + bias; optional GELU (tanh approx, jax default) ----
__global__ __launch_bounds__(256)
void finalize(float* __restrict__ x, const float* __restrict__ bias, int do_gelu) {
    int i = blockIdx.x * 256 + threadIdx.x;
    if (i >= NN * D) return;
    float v = x[i] + bias[i & (D - 1)];
    if (do_gelu) {
        float u = 0.7978845608028654f * (v + 0.044715f * v * v * v);
        v = 0.5f * v * (1.f + tanhf(u));
    }
    x[i] = v;
}

// ---- K8: column-sum pool (scaled later) ----
__global__ __launch_bounds__(128)
void pool(const float* __restrict__ x, float* __restrict__ pooled) {
    int c = threadIdx.x;
    int chunk = (NN + gridDim.x - 1) / gridDim.x;
    int n0 = blockIdx.x * chunk;
    int n1 = n0 + chunk; if (n1 > NN) n1 = NN;
    float acc = 0.f;
    for (int n = n0; n < n1; ++n) acc += x[n * D + c];
    atomicAdd(pooled + c, acc);
}

// ---- K9: logits = (pooled/NN) @ Wc + bc ; 1 wave per class ----
__global__ __launch_bounds__(640)
void classify(const float* __restrict__ pooled, const float* __restrict__ Wc,
              const float* __restrict__ bc, float* __restrict__ out) {
    int k = threadIdx.x >> 6;
    int lane = threadIdx.x & 63;
    float acc = 0.f;
    for (int d = lane; d < D; d += 64)
        acc += pooled[d] * (1.0f / NN) * Wc[d * NCLS + k];
#pragma unroll
    for (int off = 32; off; off >>= 1) acc += __shfl_down(acc, off);
    if (lane == 0) out[k] = acc + bc[k];
}

extern "C" void kernel_launch(void* const* d_in, const int* in_sizes, int n_in,
                              void* d_out, int out_size, void* d_ws, size_t ws_size,
                              hipStream_t stream) {
    const int*   feats = (const int*)d_in[0];
    const int*   edges = (const int*)d_in[1];
    const float* emb   = (const float*)d_in[2];
    const float* W     = (const float*)d_in[3];
    const float* asrcW = (const float*)d_in[4];
    const float* adstW = (const float*)d_in[5];
    const float* bias  = (const float*)d_in[6];
    const float* Wc    = (const float*)d_in[7];
    const float* bc    = (const float*)d_in[8];
    float* out = (float*)d_out;

    const int* srcp = edges;
    const int* dstp = edges + NE;

    char* ws = (char*)d_ws;
    size_t off = 0;
    float*    hbuf  = (float*)(ws + off); off += (size_t)NN * HC * 4;   // 20.48 MB
    float*    xb0   = (float*)(ws + off); off += (size_t)NN * D * 4;    // 5.12 MB
    float*    xb1   = (float*)(ws + off); off += (size_t)NN * D * 4;    // 5.12 MB
    float*    ebuf  = (float*)(ws + off); off += (size_t)NE * NH * 4;   // 2.56 MB
    float*    asrc  = (float*)(ws + off); off += (size_t)NN * NH * 4;
    float*    adst  = (float*)(ws + off); off += (size_t)NN * NH * 4;
    unsigned* menc  = (unsigned*)(ws + off); off += (size_t)NN * NH * 4;
    float*    ssum  = (float*)(ws + off); off += (size_t)NN * NH * 4;
    float*    pooled= (float*)(ws + off); off += D * 4;

    atom_encoder<<<NN, 128, 0, stream>>>(feats, emb, xb0);

    float* xin = xb0;
    float* xout = xb1;
    for (int l = 0; l < 3; ++l) {
        gemm64<<<dim3((NN + BM - 1) / BM, HC / BN), 256, 0, stream>>>(
            xin, W + (size_t)l * D * HC, hbuf);
        alphas<<<NN, 64, 0, stream>>>(hbuf, asrcW + (size_t)l * NH * C,
                                      adstW + (size_t)l * NH * C, asrc, adst);
        init_menc<<<(NN * NH + 255) / 256, 256, 0, stream>>>(menc);
        hipMemsetAsync(ssum, 0, (size_t)NN * NH * 4, stream);
        hipMemsetAsync(xout, 0, (size_t)NN * D * 4, stream);
        edge_scores<<<NE / 256, 256, 0, stream>>>(srcp, dstp, asrc, adst, ebuf, menc);
        edge_exp<<<NE / 256, 256, 0, stream>>>(dstp, ebuf, menc, ssum);
        edge_alpha<<<NE / 256, 256, 0, stream>>>(dstp, ebuf, ssum);
        aggregate<<<(NE * 32) / 256, 256, 0, stream>>>(srcp, dstp, ebuf, hbuf, xout);
        finalize<<<(NN * D + 255) / 256, 256, 0, stream>>>(xout, bias + (size_t)l * D, l < 2 ? 1 : 0);
        float* tmp = xin; xin = xout; xout = tmp;
    }

    hipMemsetAsync(pooled, 0, D * 4, stream);
    pool<<<64, 128, 0, stream>>>(xin, pooled);
    classify<<<1, 640, 0, stream>>>(pooled, Wc, bc, out);
}

// Round 2
// 371.643 us; speedup vs baseline: 3.4444x; 3.4444x over previous
//
#include <hip/hip_runtime.h>
#include <hip/hip_bf16.h>
#include <math.h>

#define NN 10000      // nodes
#define NE 160000     // edges
#define NF 9          // atom features
#define VOCAB 128
#define D 128
#define NH 4          // heads
#define C 128
#define HC 512        // NH*C
#define NCLS 10

// ---- K0: atom encoder: x[n,d] = sum_f emb[f, feat[n,f], d] ----
__global__ __launch_bounds__(128)
void atom_encoder(const int* __restrict__ feats, const float* __restrict__ emb,
                  float* __restrict__ x) {
    int n = blockIdx.x;
    int d = threadIdx.x;
    __shared__ int f[NF];
    if (threadIdx.x < NF) f[threadIdx.x] = feats[n * NF + threadIdx.x];
    __syncthreads();
    float acc = 0.f;
#pragma unroll
    for (int i = 0; i < NF; ++i)
        acc += emb[(i * VOCAB + f[i]) * D + d];
    x[n * D + d] = acc;
}

// ---- K1: fp32 GEMM h = x @ W_l  ([NN,128] @ [128,512]) ----
#define BM 64
#define BN 64
#define BK 32
__global__ __launch_bounds__(256)
void gemm64(const float* __restrict__ X, const float* __restrict__ Wm,
            float* __restrict__ Hh) {
    __shared__ float sA[BK][BM];
    __shared__ float sB[BK][BN];
    int t = threadIdx.x;
    int bm = blockIdx.x * BM;
    int bn = blockIdx.y * BN;
    int tr = t >> 4, tc = t & 15;
    float acc[4][4] = {};
    for (int kk = 0; kk < D; kk += BK) {
#pragma unroll
        for (int i = 0; i < 2; ++i) {           // A: 64x32, transposed store
            int j = t + i * 256;
            int row = j >> 3, kc = (j & 7) * 4;
            float4 v = make_float4(0.f, 0.f, 0.f, 0.f);
            int gr = bm + row;
            if (gr < NN) v = *(const float4*)(X + gr * D + kk + kc);
            sA[kc + 0][row] = v.x; sA[kc + 1][row] = v.y;
            sA[kc + 2][row] = v.z; sA[kc + 3][row] = v.w;
        }
#pragma unroll
        for (int i = 0; i < 2; ++i) {           // B: 32x64, direct float4
            int j = t + i * 256;
            int kr = j >> 4, cc = (j & 15) * 4;
            *(float4*)&sB[kr][cc] = *(const float4*)(Wm + (kk + kr) * HC + bn + cc);
        }
        __syncthreads();
#pragma unroll
        for (int k = 0; k < BK; ++k) {
            float4 a = *(const float4*)&sA[k][tr * 4];
            float4 b = *(const float4*)&sB[k][tc * 4];
            float av[4] = {a.x, a.y, a.z, a.w};
            float bv[4] = {b.x, b.y, b.z, b.w};
#pragma unroll
            for (int mi = 0; mi < 4; ++mi)
#pragma unroll
                for (int ni = 0; ni < 4; ++ni)
                    acc[mi][ni] = fmaf(av[mi], bv[ni], acc[mi][ni]);
        }
        __syncthreads();
    }
#pragma unroll
    for (int mi = 0; mi < 4; ++mi) {
        int gr = bm + tr * 4 + mi;
        if (gr < NN)
            *(float4*)(Hh + gr * HC + bn + tc * 4) =
                make_float4(acc[mi][0], acc[mi][1], acc[mi][2], acc[mi][3]);
    }
}

// ---- K2: per-node attention coefficients (src & dst), 1 wave per node ----
__global__ __launch_bounds__(64)
void alphas(const float* __restrict__ Hh, const float* __restrict__ as_,
            const float* __restrict__ ad_, float* __restrict__ alpha_src,
            float* __restrict__ alpha_dst) {
    int n = blockIdx.x;
    int lane = threadIdx.x;
    const float* hn = Hh + n * HC;
#pragma unroll
    for (int h = 0; h < NH; ++h) {
        float x0 = hn[h * C + lane], x1 = hn[h * C + lane + 64];
        float s = x0 * as_[h * C + lane] + x1 * as_[h * C + lane + 64];
        float d = x0 * ad_[h * C + lane] + x1 * ad_[h * C + lane + 64];
#pragma unroll
        for (int off = 32; off; off >>= 1) {
            s += __shfl_down(s, off);
            d += __shfl_down(d, off);
        }
        if (lane == 0) { alpha_src[n * NH + h] = s; alpha_dst[n * NH + h] = d; }
    }
}

// ---- CSR build: histogram of dst ----
__global__ __launch_bounds__(256)
void hist(const int* __restrict__ dst, int* __restrict__ deg) {
    int e = blockIdx.x * 256 + threadIdx.x;
    if (e < NE) atomicAdd(&deg[dst[e]], 1);
}

// ---- CSR build: one-block exclusive scan of deg[NN] -> rowstart, cursor ----
#define SCAN_T 1024
#define SCAN_PER ((NN + SCAN_T - 1) / SCAN_T)   // 10
__global__ __launch_bounds__(SCAN_T)
void scan_deg(const int* __restrict__ deg, int* __restrict__ rowstart,
              int* __restrict__ cursor) {
    __shared__ int part[SCAN_T];
    int t = threadIdx.x;
    int base = t * SCAN_PER;
    int vals[SCAN_PER];
    int loc = 0;
#pragma unroll
    for (int i = 0; i < SCAN_PER; ++i) {
        int idx = base + i;
        int v = (idx < NN) ? deg[idx] : 0;
        vals[i] = v;
        loc += v;
    }
    part[t] = loc;
    __syncthreads();
    for (int off = 1; off < SCAN_T; off <<= 1) {
        int y = (t >= off) ? part[t - off] : 0;
        __syncthreads();
        part[t] += y;
        __syncthreads();
    }
    int run = part[t] - loc;   // exclusive prefix
#pragma unroll
    for (int i = 0; i < SCAN_PER; ++i) {
        int idx = base + i;
        if (idx < NN) { rowstart[idx] = run; cursor[idx] = run; }
        run += vals[i];
    }
}

// ---- CSR build: scatter src sorted by dst ----
__global__ __launch_bounds__(256)
void scatter(const int* __restrict__ src, const int* __restrict__ dst,
             int* __restrict__ cursor, int* __restrict__ csr_src) {
    int e = blockIdx.x * 256 + threadIdx.x;
    if (e < NE) {
        int p = atomicAdd(&cursor[dst[e]], 1);
        csr_src[p] = src[e];
    }
}

// ---- K3: fused per-dst-node softmax + aggregation + bias + gelu ----
// one block (128 threads) per destination node; zero atomics
__global__ __launch_bounds__(128)
void gat_fused(const int* __restrict__ csr_src, const int* __restrict__ rowstart,
               const int* __restrict__ degA, const float* __restrict__ asr,
               const float* __restrict__ adr, const float* __restrict__ Hh,
               const float* __restrict__ bias, float* __restrict__ xout,
               int do_gelu) {
    int n = blockIdx.x;
    int t = threadIdx.x;
    int deg = degA[n];
    int start = rowstart[n];

    __shared__ float smax[NH];
    __shared__ float sinv[NH];
    __shared__ float lal[128][NH];
    __shared__ int lsrc[128];

    // ---- phase A: per-head segment max and exp-sum (32 lanes per head) ----
    int h = t >> 5, i = t & 31;
    float ad_h = adr[n * NH + h];
    float mx = -INFINITY;
    for (int j = i; j < deg; j += 32) {
        int s = csr_src[start + j];
        float v = asr[s * NH + h] + ad_h;
        v = v >= 0.f ? v : 0.2f * v;
        mx = fmaxf(mx, v);
    }
#pragma unroll
    for (int off = 16; off; off >>= 1) mx = fmaxf(mx, __shfl_xor(mx, off));
    if (i == 0) smax[h] = mx;
    __syncthreads();
    float m = smax[h];
    float ss = 0.f;
    for (int j = i; j < deg; j += 32) {
        int s = csr_src[start + j];
        float v = asr[s * NH + h] + ad_h;
        v = v >= 0.f ? v : 0.2f * v;
        ss += __expf(v - m);
    }
#pragma unroll
    for (int off = 16; off; off >>= 1) ss += __shfl_xor(ss, off);
    if (i == 0) sinv[h] = 0.25f / (ss + 1e-16f);   // fold head-mean 1/NH
    __syncthreads();

    // ---- phase B: aggregate; thread t owns channel t ----
    float m0 = smax[0], m1 = smax[1], m2 = smax[2], m3 = smax[3];
    float i0 = sinv[0], i1 = sinv[1], i2 = sinv[2], i3 = sinv[3];
    float a0 = adr[n * NH + 0], a1 = adr[n * NH + 1];
    float a2 = adr[n * NH + 2], a3 = adr[n * NH + 3];
    float acc = 0.f;

    for (int cb = 0; cb < deg; cb += 128) {
        int cl = deg - cb; if (cl > 128) cl = 128;
        if (t < cl) {
            int s = csr_src[start + cb + t];
            float4 av = *(const float4*)(asr + s * NH);
            float v0 = av.x + a0; v0 = v0 >= 0.f ? v0 : 0.2f * v0;
            float v1 = av.y + a1; v1 = v1 >= 0.f ? v1 : 0.2f * v1;
            float v2 = av.z + a2; v2 = v2 >= 0.f ? v2 : 0.2f * v2;
            float v3 = av.w + a3; v3 = v3 >= 0.f ? v3 : 0.2f * v3;
            lal[t][0] = __expf(v0 - m0) * i0;
            lal[t][1] = __expf(v1 - m1) * i1;
            lal[t][2] = __expf(v2 - m2) * i2;
            lal[t][3] = __expf(v3 - m3) * i3;
            lsrc[t] = s;
        }
        __syncthreads();
        for (int j = 0; j < cl; ++j) {
            int s = lsrc[j];
            const float* hp = Hh + (size_t)s * HC + t;
            float4 w = *(const float4*)lal[j];
            acc += w.x * hp[0] + w.y * hp[C] + w.z * hp[2 * C] + w.w * hp[3 * C];
        }
        __syncthreads();
    }

    float v = acc + bias[t];
    if (do_gelu) {
        float u = 0.7978845608028654f * (v + 0.044715f * v * v * v);
        v = 0.5f * v * (1.f + tanhf(u));
    }
    xout[n * D + t] = v;
}

// ---- K8: column-sum pool (scaled in classify) ----
__global__ __launch_bounds__(128)
void pool(const float* __restrict__ x, float* __restrict__ pooled) {
    int c = threadIdx.x;
    int chunk = (NN + gridDim.x - 1) / gridDim.x;
    int n0 = blockIdx.x * chunk;
    int n1 = n0 + chunk; if (n1 > NN) n1 = NN;
    float acc = 0.f;
    for (int n = n0; n < n1; ++n) acc += x[n * D + c];
    atomicAdd(pooled + c, acc);
}

// ---- K9: logits = (pooled/NN) @ Wc + bc ; 1 wave per class ----
__global__ __launch_bounds__(640)
void classify(const float* __restrict__ pooled, const float* __restrict__ Wc,
              const float* __restrict__ bc, float* __restrict__ out) {
    int k = threadIdx.x >> 6;
    int lane = threadIdx.x & 63;
    float acc = 0.f;
    for (int d = lane; d < D; d += 64)
        acc += pooled[d] * (1.0f / NN) * Wc[d * NCLS + k];
#pragma unroll
    for (int off = 32; off; off >>= 1) acc += __shfl_down(acc, off);
    if (lane == 0) out[k] = acc + bc[k];
}

extern "C" void kernel_launch(void* const* d_in, const int* in_sizes, int n_in,
                              void* d_out, int out_size, void* d_ws, size_t ws_size,
                              hipStream_t stream) {
    const int*   feats = (const int*)d_in[0];
    const int*   edges = (const int*)d_in[1];
    const float* emb   = (const float*)d_in[2];
    const float* W     = (const float*)d_in[3];
    const float* asrcW = (const float*)d_in[4];
    const float* adstW = (const float*)d_in[5];
    const float* bias  = (const float*)d_in[6];
    const float* Wc    = (const float*)d_in[7];
    const float* bc    = (const float*)d_in[8];
    float* out = (float*)d_out;

    const int* srcp = edges;
    const int* dstp = edges + NE;

    char* ws = (char*)d_ws;
    size_t off = 0;
    float* hbuf   = (float*)(ws + off); off += (size_t)NN * HC * 4;   // 20.48 MB
    float* xb0    = (float*)(ws + off); off += (size_t)NN * D * 4;    // 5.12 MB
    float* xb1    = (float*)(ws + off); off += (size_t)NN * D * 4;    // 5.12 MB
    float* asrc   = (float*)(ws + off); off += (size_t)NN * NH * 4;
    float* adst   = (float*)(ws + off); off += (size_t)NN * NH * 4;
    int*   deg    = (int*)(ws + off);   off += (size_t)NN * 4;
    int*   rowst  = (int*)(ws + off);   off += (size_t)NN * 4;
    int*   cursor = (int*)(ws + off);   off += (size_t)NN * 4;
    int*   csrsrc = (int*)(ws + off);   off += (size_t)NE * 4;        // 0.64 MB
    float* pooled = (float*)(ws + off); off += D * 4;

    // ---- build CSR (dst-sorted) once per call ----
    hipMemsetAsync(deg, 0, (size_t)NN * 4, stream);
    hist<<<(NE + 255) / 256, 256, 0, stream>>>(dstp, deg);
    scan_deg<<<1, SCAN_T, 0, stream>>>(deg, rowst, cursor);
    scatter<<<(NE + 255) / 256, 256, 0, stream>>>(srcp, dstp, cursor, csrsrc);

    atom_encoder<<<NN, 128, 0, stream>>>(feats, emb, xb0);

    float* xin = xb0;
    float* xout = xb1;
    for (int l = 0; l < 3; ++l) {
        gemm64<<<dim3((NN + BM - 1) / BM, HC / BN), 256, 0, stream>>>(
            xin, W + (size_t)l * D * HC, hbuf);
        alphas<<<NN, 64, 0, stream>>>(hbuf, asrcW + (size_t)l * NH * C,
                                      adstW + (size_t)l * NH * C, asrc, adst);
        gat_fused<<<NN, 128, 0, stream>>>(csrsrc, rowst, deg, asrc, adst, hbuf,
                                          bias + (size_t)l * D, xout, l < 2 ? 1 : 0);
        float* tmp = xin; xin = xout; xout = tmp;
    }

    hipMemsetAsync(pooled, 0, D * 4, stream);
    pool<<<64, 128, 0, stream>>>(xin, pooled);
    classify<<<1, 640, 0, stream>>>(pooled, Wc, bc, out);
}

// Round 3
// 369.626 us; speedup vs baseline: 3.4632x; 1.0055x over previous
//
#include <hip/hip_runtime.h>
#include <hip/hip_bf16.h>
#include <math.h>

#define NN 10000      // nodes
#define NE 160000     // edges
#define NF 9          // atom features
#define VOCAB 128
#define D 128
#define NH 4          // heads
#define C 128
#define HC 512        // NH*C
#define NCLS 10
#define NL 3

// ---- K0: atom encoder: x[n,d] = sum_f emb[f, feat[n,f], d] ----
__global__ __launch_bounds__(128)
void atom_encoder(const int* __restrict__ feats, const float* __restrict__ emb,
                  float* __restrict__ x) {
    int n = blockIdx.x;
    int d = threadIdx.x;
    __shared__ int f[NF];
    if (threadIdx.x < NF) f[threadIdx.x] = feats[n * NF + threadIdx.x];
    __syncthreads();
    float acc = 0.f;
#pragma unroll
    for (int i = 0; i < NF; ++i)
        acc += emb[(i * VOCAB + f[i]) * D + d];
    x[n * D + d] = acc;
}

// ---- CSR build: histogram of dst ----
__global__ __launch_bounds__(256)
void hist(const int* __restrict__ dst, int* __restrict__ deg) {
    int e = blockIdx.x * 256 + threadIdx.x;
    if (e < NE) atomicAdd(&deg[dst[e]], 1);
}

// ---- CSR build: one-block exclusive scan of deg[NN] -> rowstart, cursor ----
#define SCAN_T 1024
#define SCAN_PER ((NN + SCAN_T - 1) / SCAN_T)   // 10
__global__ __launch_bounds__(SCAN_T)
void scan_deg(const int* __restrict__ deg, int* __restrict__ rowstart,
              int* __restrict__ cursor) {
    __shared__ int part[SCAN_T];
    int t = threadIdx.x;
    int base = t * SCAN_PER;
    int vals[SCAN_PER];
    int loc = 0;
#pragma unroll
    for (int i = 0; i < SCAN_PER; ++i) {
        int idx = base + i;
        int v = (idx < NN) ? deg[idx] : 0;
        vals[i] = v;
        loc += v;
    }
    part[t] = loc;
    __syncthreads();
    for (int off = 1; off < SCAN_T; off <<= 1) {
        int y = (t >= off) ? part[t - off] : 0;
        __syncthreads();
        part[t] += y;
        __syncthreads();
    }
    int run = part[t] - loc;   // exclusive prefix
#pragma unroll
    for (int i = 0; i < SCAN_PER; ++i) {
        int idx = base + i;
        if (idx < NN) { rowstart[idx] = run; cursor[idx] = run; }
        run += vals[i];
    }
}

// ---- CSR build: scatter src sorted by dst ----
__global__ __launch_bounds__(256)
void scatter(const int* __restrict__ src, const int* __restrict__ dst,
             int* __restrict__ cursor, int* __restrict__ csr_src) {
    int e = blockIdx.x * 256 + threadIdx.x;
    if (e < NE) {
        int p = atomicAdd(&cursor[dst[e]], 1);
        csr_src[p] = src[e];
    }
}

// ---- P0: wsrc[l][h] = W_l,h @ a_s[l,h]; wdst likewise (24 blocks) ----
__global__ __launch_bounds__(128)
void prep_att(const float* __restrict__ W, const float* __restrict__ as_,
              const float* __restrict__ ad_, float* __restrict__ wsrc,
              float* __restrict__ wdst) {
    int l = blockIdx.x >> 3;
    int r = blockIdx.x & 7;
    int h = r >> 1;
    int side = r & 1;
    int k = threadIdx.x;
    const float* av = (side ? ad_ : as_) + (size_t)(l * NH + h) * C;
    const float* wrow = W + (size_t)l * D * HC + (size_t)k * HC + h * C;
    float acc = 0.f;
#pragma unroll 4
    for (int c = 0; c < C; ++c) acc += wrow[c] * av[c];
    float* o = (side ? wdst : wsrc) + (size_t)(l * NH + h) * D + k;
    *o = acc;
}

// ---- K2: alpha_src/dst[n,h] = x[n] . wvec[h]  (4 nodes per 256-thr block) ----
__global__ __launch_bounds__(256)
void alphas2(const float* __restrict__ X, const float* __restrict__ wsrc,
             const float* __restrict__ wdst, float* __restrict__ asrc,
             float* __restrict__ adst) {
    int n = blockIdx.x * 4 + (threadIdx.x >> 6);
    int lane = threadIdx.x & 63;
    float x0 = X[n * D + lane], x1 = X[n * D + lane + 64];
#pragma unroll
    for (int h = 0; h < NH; ++h) {
        float s = x0 * wsrc[h * D + lane] + x1 * wsrc[h * D + lane + 64];
        float d = x0 * wdst[h * D + lane] + x1 * wdst[h * D + lane + 64];
#pragma unroll
        for (int off = 32; off; off >>= 1) {
            s += __shfl_down(s, off);
            d += __shfl_down(d, off);
        }
        if (lane == 0) { asrc[n * NH + h] = s; adst[n * NH + h] = d; }
    }
}

// ---- K3: fused per-dst softmax + aggregation of x -> agg[n, h*D+d] ----
__global__ __launch_bounds__(128)
void gat_agg(const int* __restrict__ csr_src, const int* __restrict__ rowstart,
             const int* __restrict__ degA, const float* __restrict__ asr,
             const float* __restrict__ adr, const float* __restrict__ X,
             float* __restrict__ agg) {
    int n = blockIdx.x;
    int t = threadIdx.x;
    int deg = degA[n];
    int start = rowstart[n];

    __shared__ float smax[NH];
    __shared__ float sinv[NH];
    __shared__ float lal[128][NH];
    __shared__ int lsrc[128];

    // ---- phase A: per-head segment max and exp-sum (32 lanes per head) ----
    int h = t >> 5, i = t & 31;
    float ad_h = adr[n * NH + h];
    float mx = -INFINITY;
    for (int j = i; j < deg; j += 32) {
        int s = csr_src[start + j];
        float v = asr[s * NH + h] + ad_h;
        v = v >= 0.f ? v : 0.2f * v;
        mx = fmaxf(mx, v);
    }
#pragma unroll
    for (int off = 16; off; off >>= 1) mx = fmaxf(mx, __shfl_xor(mx, off));
    if (i == 0) smax[h] = mx;
    __syncthreads();
    float m = smax[h];
    float ss = 0.f;
    for (int j = i; j < deg; j += 32) {
        int s = csr_src[start + j];
        float v = asr[s * NH + h] + ad_h;
        v = v >= 0.f ? v : 0.2f * v;
        ss += __expf(v - m);
    }
#pragma unroll
    for (int off = 16; off; off >>= 1) ss += __shfl_xor(ss, off);
    if (i == 0) sinv[h] = 0.25f / (ss + 1e-16f);   // fold head-mean 1/NH
    __syncthreads();

    // ---- phase B: thread t owns channel d=t; 4 head accumulators ----
    float m0 = smax[0], m1 = smax[1], m2 = smax[2], m3 = smax[3];
    float i0 = sinv[0], i1 = sinv[1], i2 = sinv[2], i3 = sinv[3];
    float a0 = adr[n * NH + 0], a1 = adr[n * NH + 1];
    float a2 = adr[n * NH + 2], a3 = adr[n * NH + 3];
    float acc0 = 0.f, acc1 = 0.f, acc2 = 0.f, acc3 = 0.f;

    for (int cb = 0; cb < deg; cb += 128) {
        int cl = deg - cb; if (cl > 128) cl = 128;
        if (t < cl) {
            int s = csr_src[start + cb + t];
            float4 av = *(const float4*)(asr + s * NH);
            float v0 = av.x + a0; v0 = v0 >= 0.f ? v0 : 0.2f * v0;
            float v1 = av.y + a1; v1 = v1 >= 0.f ? v1 : 0.2f * v1;
            float v2 = av.z + a2; v2 = v2 >= 0.f ? v2 : 0.2f * v2;
            float v3 = av.w + a3; v3 = v3 >= 0.f ? v3 : 0.2f * v3;
            lal[t][0] = __expf(v0 - m0) * i0;
            lal[t][1] = __expf(v1 - m1) * i1;
            lal[t][2] = __expf(v2 - m2) * i2;
            lal[t][3] = __expf(v3 - m3) * i3;
            lsrc[t] = s;
        }
        __syncthreads();
#pragma unroll 4
        for (int j = 0; j < cl; ++j) {
            float xv = X[(size_t)lsrc[j] * D + t];
            float4 w = *(const float4*)lal[j];
            acc0 += w.x * xv;
            acc1 += w.y * xv;
            acc2 += w.z * xv;
            acc3 += w.w * xv;
        }
        __syncthreads();
    }

    float* o = agg + (size_t)n * HC + t;
    o[0 * D] = acc0;
    o[1 * D] = acc1;
    o[2 * D] = acc2;
    o[3 * D] = acc3;
}

// ---- K4: out = agg @ B2 + bias (+gelu); B2[h*128+k, c] = W[k, h*128+c] ----
#define BM 64
#define BN 64
#define BK 32
__global__ __launch_bounds__(256)
void gemm_out(const float* __restrict__ A, const float* __restrict__ Wm,
              const float* __restrict__ bias, float* __restrict__ Out,
              int do_gelu) {
    __shared__ float sA[BK][BM];
    __shared__ float sB[BK][BN];
    int t = threadIdx.x;
    int bm = blockIdx.x * BM;
    int bn = blockIdx.y * BN;
    int tr = t >> 4, tc = t & 15;
    float acc[4][4] = {};
    for (int kk = 0; kk < HC; kk += BK) {
#pragma unroll
        for (int i = 0; i < 2; ++i) {           // A: 64x32, transposed store
            int j = t + i * 256;
            int row = j >> 3, kc = (j & 7) * 4;
            float4 v = make_float4(0.f, 0.f, 0.f, 0.f);
            int gr = bm + row;
            if (gr < NN) v = *(const float4*)(A + (size_t)gr * HC + kk + kc);
            sA[kc + 0][row] = v.x; sA[kc + 1][row] = v.y;
            sA[kc + 2][row] = v.z; sA[kc + 3][row] = v.w;
        }
#pragma unroll
        for (int i = 0; i < 2; ++i) {           // B: permuted view of W
            int jj = t + i * 256;
            int kr = jj >> 4, cc = (jj & 15) * 4;
            int j = kk + kr;                    // j = h*128 + k
            *(float4*)&sB[kr][cc] =
                *(const float4*)(Wm + (size_t)(j & 127) * HC + (j >> 7) * C + bn + cc);
        }
        __syncthreads();
#pragma unroll
        for (int k = 0; k < BK; ++k) {
            float4 a = *(const float4*)&sA[k][tr * 4];
            float4 b = *(const float4*)&sB[k][tc * 4];
            float av[4] = {a.x, a.y, a.z, a.w};
            float bv[4] = {b.x, b.y, b.z, b.w};
#pragma unroll
            for (int mi = 0; mi < 4; ++mi)
#pragma unroll
                for (int ni = 0; ni < 4; ++ni)
                    acc[mi][ni] = fmaf(av[mi], bv[ni], acc[mi][ni]);
        }
        __syncthreads();
    }
#pragma unroll
    for (int mi = 0; mi < 4; ++mi) {
        int gr = bm + tr * 4 + mi;
        if (gr >= NN) continue;
        float4 r;
        float* rp = &r.x;
#pragma unroll
        for (int ni = 0; ni < 4; ++ni) {
            float v = acc[mi][ni] + bias[bn + tc * 4 + ni];
            if (do_gelu) {
                float u = 0.7978845608028654f * (v + 0.044715f * v * v * v);
                v = 0.5f * v * (1.f + tanhf(u));
            }
            rp[ni] = v;
        }
        *(float4*)(Out + (size_t)gr * D + bn + tc * 4) = r;
    }
}

// ---- K8: column-sum pool (scaled in classify) ----
__global__ __launch_bounds__(128)
void pool(const float* __restrict__ x, float* __restrict__ pooled) {
    int c = threadIdx.x;
    int chunk = (NN + gridDim.x - 1) / gridDim.x;
    int n0 = blockIdx.x * chunk;
    int n1 = n0 + chunk; if (n1 > NN) n1 = NN;
    float acc = 0.f;
    for (int n = n0; n < n1; ++n) acc += x[n * D + c];
    atomicAdd(pooled + c, acc);
}

// ---- K9: logits = (pooled/NN) @ Wc + bc ; 1 wave per class ----
__global__ __launch_bounds__(640)
void classify(const float* __restrict__ pooled, const float* __restrict__ Wc,
              const float* __restrict__ bc, float* __restrict__ out) {
    int k = threadIdx.x >> 6;
    int lane = threadIdx.x & 63;
    float acc = 0.f;
    for (int d = lane; d < D; d += 64)
        acc += pooled[d] * (1.0f / NN) * Wc[d * NCLS + k];
#pragma unroll
    for (int off = 32; off; off >>= 1) acc += __shfl_down(acc, off);
    if (lane == 0) out[k] = acc + bc[k];
}

extern "C" void kernel_launch(void* const* d_in, const int* in_sizes, int n_in,
                              void* d_out, int out_size, void* d_ws, size_t ws_size,
                              hipStream_t stream) {
    const int*   feats = (const int*)d_in[0];
    const int*   edges = (const int*)d_in[1];
    const float* emb   = (const float*)d_in[2];
    const float* W     = (const float*)d_in[3];
    const float* asrcW = (const float*)d_in[4];
    const float* adstW = (const float*)d_in[5];
    const float* bias  = (const float*)d_in[6];
    const float* Wc    = (const float*)d_in[7];
    const float* bc    = (const float*)d_in[8];
    float* out = (float*)d_out;

    const int* srcp = edges;
    const int* dstp = edges + NE;

    char* ws = (char*)d_ws;
    size_t off = 0;
    float* aggb   = (float*)(ws + off); off += (size_t)NN * HC * 4;   // 20.48 MB
    float* xb0    = (float*)(ws + off); off += (size_t)NN * D * 4;    // 5.12 MB
    float* xb1    = (float*)(ws + off); off += (size_t)NN * D * 4;    // 5.12 MB
    float* asrc   = (float*)(ws + off); off += (size_t)NN * NH * 4;
    float* adst   = (float*)(ws + off); off += (size_t)NN * NH * 4;
    int*   deg    = (int*)(ws + off);   off += (size_t)NN * 4;
    int*   rowst  = (int*)(ws + off);   off += (size_t)NN * 4;
    int*   cursor = (int*)(ws + off);   off += (size_t)NN * 4;
    int*   csrsrc = (int*)(ws + off);   off += (size_t)NE * 4;        // 0.64 MB
    float* wsrcb  = (float*)(ws + off); off += (size_t)NL * NH * D * 4;
    float* wdstb  = (float*)(ws + off); off += (size_t)NL * NH * D * 4;
    float* pooled = (float*)(ws + off); off += D * 4;

    // ---- build CSR (dst-sorted) + fold W into attention vectors ----
    hipMemsetAsync(deg, 0, (size_t)NN * 4, stream);
    hist<<<(NE + 255) / 256, 256, 0, stream>>>(dstp, deg);
    scan_deg<<<1, SCAN_T, 0, stream>>>(deg, rowst, cursor);
    scatter<<<(NE + 255) / 256, 256, 0, stream>>>(srcp, dstp, cursor, csrsrc);
    prep_att<<<NL * NH * 2, 128, 0, stream>>>(W, asrcW, adstW, wsrcb, wdstb);

    atom_encoder<<<NN, 128, 0, stream>>>(feats, emb, xb0);

    float* xin = xb0;
    float* xout = xb1;
    for (int l = 0; l < NL; ++l) {
        alphas2<<<NN / 4, 256, 0, stream>>>(xin, wsrcb + (size_t)l * NH * D,
                                            wdstb + (size_t)l * NH * D, asrc, adst);
        gat_agg<<<NN, 128, 0, stream>>>(csrsrc, rowst, deg, asrc, adst, xin, aggb);
        gemm_out<<<dim3((NN + BM - 1) / BM, D / BN), 256, 0, stream>>>(
            aggb, W + (size_t)l * D * HC, bias + (size_t)l * D, xout, l < 2 ? 1 : 0);
        float* tmp = xin; xin = xout; xout = tmp;
    }

    hipMemsetAsync(pooled, 0, D * 4, stream);
    pool<<<64, 128, 0, stream>>>(xin, pooled);
    classify<<<1, 640, 0, stream>>>(pooled, Wc, bc, out);
}

// Round 4
// 336.474 us; speedup vs baseline: 3.8044x; 1.0985x over previous
//
#include <hip/hip_runtime.h>
#include <hip/hip_bf16.h>
#include <math.h>

#define NN 10000      // nodes
#define NE 160000     // edges
#define NF 9          // atom features
#define VOCAB 128
#define D 128
#define NH 4          // heads
#define C 128
#define HC 512        // NH*C
#define NCLS 10
#define NL 3

typedef __attribute__((ext_vector_type(8))) short bf16x8;
typedef __attribute__((ext_vector_type(4))) float f32x4;

__device__ __forceinline__ unsigned short f2bf(float f) {
    unsigned u = __float_as_uint(f);
    unsigned r = ((u >> 16) & 1u) + 0x7FFFu;
    return (unsigned short)((u + r) >> 16);
}
__device__ __forceinline__ float bf2f(unsigned short h) {
    return __uint_as_float(((unsigned)h) << 16);
}
__device__ __forceinline__ void fsplit(float v, unsigned short* hi, unsigned short* lo) {
    unsigned short h = f2bf(v);
    *hi = h;
    *lo = f2bf(v - bf2f(h));
}

// ---- K0: atom encoder: x[n,d] = sum_f emb[f, feat[n,f], d] ----
__global__ __launch_bounds__(128)
void atom_encoder(const int* __restrict__ feats, const float* __restrict__ emb,
                  float* __restrict__ x) {
    int n = blockIdx.x;
    int d = threadIdx.x;
    __shared__ int f[NF];
    if (threadIdx.x < NF) f[threadIdx.x] = feats[n * NF + threadIdx.x];
    __syncthreads();
    float acc = 0.f;
#pragma unroll
    for (int i = 0; i < NF; ++i)
        acc += emb[(i * VOCAB + f[i]) * D + d];
    x[n * D + d] = acc;
}

// ---- CSR build: histogram of dst ----
__global__ __launch_bounds__(256)
void hist(const int* __restrict__ dst, int* __restrict__ deg) {
    int e = blockIdx.x * 256 + threadIdx.x;
    if (e < NE) atomicAdd(&deg[dst[e]], 1);
}

// ---- CSR build: one-block exclusive scan of deg[NN] -> rowstart, cursor ----
#define SCAN_T 1024
#define SCAN_PER ((NN + SCAN_T - 1) / SCAN_T)   // 10
__global__ __launch_bounds__(SCAN_T)
void scan_deg(const int* __restrict__ deg, int* __restrict__ rowstart,
              int* __restrict__ cursor) {
    __shared__ int part[SCAN_T];
    int t = threadIdx.x;
    int base = t * SCAN_PER;
    int vals[SCAN_PER];
    int loc = 0;
#pragma unroll
    for (int i = 0; i < SCAN_PER; ++i) {
        int idx = base + i;
        int v = (idx < NN) ? deg[idx] : 0;
        vals[i] = v;
        loc += v;
    }
    part[t] = loc;
    __syncthreads();
    for (int off = 1; off < SCAN_T; off <<= 1) {
        int y = (t >= off) ? part[t - off] : 0;
        __syncthreads();
        part[t] += y;
        __syncthreads();
    }
    int run = part[t] - loc;   // exclusive prefix
#pragma unroll
    for (int i = 0; i < SCAN_PER; ++i) {
        int idx = base + i;
        if (idx < NN) { rowstart[idx] = run; cursor[idx] = run; }
        run += vals[i];
    }
}

// ---- CSR build: scatter src sorted by dst ----
__global__ __launch_bounds__(256)
void scatter(const int* __restrict__ src, const int* __restrict__ dst,
             int* __restrict__ cursor, int* __restrict__ csr_src) {
    int e = blockIdx.x * 256 + threadIdx.x;
    if (e < NE) {
        int p = atomicAdd(&cursor[dst[e]], 1);
        csr_src[p] = src[e];
    }
}

// ---- P0: wsrc[l][h] = W_l,h @ a_s[l,h]; wdst likewise (24 blocks) ----
__global__ __launch_bounds__(128)
void prep_att(const float* __restrict__ W, const float* __restrict__ as_,
              const float* __restrict__ ad_, float* __restrict__ wsrc,
              float* __restrict__ wdst) {
    int l = blockIdx.x >> 3;
    int r = blockIdx.x & 7;
    int h = r >> 1;
    int side = r & 1;
    int k = threadIdx.x;
    const float* av = (side ? ad_ : as_) + (size_t)(l * NH + h) * C;
    const float* wrow = W + (size_t)l * D * HC + (size_t)k * HC + h * C;
    float acc = 0.f;
#pragma unroll 4
    for (int c = 0; c < C; ++c) acc += wrow[c] * av[c];
    float* o = (side ? wdst : wsrc) + (size_t)(l * NH + h) * D + k;
    *o = acc;
}

// ---- P1: transpose+permute+split W (layers 0,1) -> Bt[l][c][j], j=h*128+k ----
// Bt[l][c][j] = W[l][j&127][(j>>7)*128 + c], split into bf16 hi/lo
__global__ __launch_bounds__(512)
void prep_w(const float* __restrict__ W, unsigned short* __restrict__ Bth,
            unsigned short* __restrict__ Btl) {
    int l = blockIdx.x >> 7;
    int c = blockIdx.x & 127;
    int j = threadIdx.x;
    float v = W[(size_t)l * D * HC + (size_t)(j & 127) * HC + (j >> 7) * C + c];
    unsigned short h, lo;
    fsplit(v, &h, &lo);
    size_t o = (size_t)(l * 128 + c) * HC + j;
    Bth[o] = h;
    Btl[o] = lo;
}

// ---- K2: alpha_src/dst[n,h] = x[n] . wvec[h]  (4 nodes per 256-thr block) ----
__global__ __launch_bounds__(256)
void alphas2(const float* __restrict__ X, const float* __restrict__ wsrc,
             const float* __restrict__ wdst, float* __restrict__ asrc,
             float* __restrict__ adst) {
    int n = blockIdx.x * 4 + (threadIdx.x >> 6);
    int lane = threadIdx.x & 63;
    float x0 = X[n * D + lane], x1 = X[n * D + lane + 64];
#pragma unroll
    for (int h = 0; h < NH; ++h) {
        float s = x0 * wsrc[h * D + lane] + x1 * wsrc[h * D + lane + 64];
        float d = x0 * wdst[h * D + lane] + x1 * wdst[h * D + lane + 64];
#pragma unroll
        for (int off = 32; off; off >>= 1) {
            s += __shfl_down(s, off);
            d += __shfl_down(d, off);
        }
        if (lane == 0) { asrc[n * NH + h] = s; adst[n * NH + h] = d; }
    }
}

// ---- K3: fused per-dst softmax + aggregation of x -> agg bf16 hi/lo ----
__global__ __launch_bounds__(128)
void gat_agg(const int* __restrict__ csr_src, const int* __restrict__ rowstart,
             const int* __restrict__ degA, const float* __restrict__ asr,
             const float* __restrict__ adr, const float* __restrict__ X,
             unsigned short* __restrict__ aggh, unsigned short* __restrict__ aggl) {
    int n = blockIdx.x;
    int t = threadIdx.x;
    int deg = degA[n];
    int start = rowstart[n];

    __shared__ float smax[NH];
    __shared__ float sinv[NH];
    __shared__ float lal[128][NH];
    __shared__ int lsrc[128];

    // ---- phase A: per-head segment max and exp-sum (32 lanes per head) ----
    int h = t >> 5, i = t & 31;
    float ad_h = adr[n * NH + h];
    float mx = -INFINITY;
    for (int j = i; j < deg; j += 32) {
        int s = csr_src[start + j];
        float v = asr[s * NH + h] + ad_h;
        v = v >= 0.f ? v : 0.2f * v;
        mx = fmaxf(mx, v);
    }
#pragma unroll
    for (int off = 16; off; off >>= 1) mx = fmaxf(mx, __shfl_xor(mx, off));
    if (i == 0) smax[h] = mx;
    __syncthreads();
    float m = smax[h];
    float ss = 0.f;
    for (int j = i; j < deg; j += 32) {
        int s = csr_src[start + j];
        float v = asr[s * NH + h] + ad_h;
        v = v >= 0.f ? v : 0.2f * v;
        ss += __expf(v - m);
    }
#pragma unroll
    for (int off = 16; off; off >>= 1) ss += __shfl_xor(ss, off);
    if (i == 0) sinv[h] = 0.25f / (ss + 1e-16f);   // fold head-mean 1/NH
    __syncthreads();

    // ---- phase B: thread t owns channel d=t; 4 head accumulators ----
    float m0 = smax[0], m1 = smax[1], m2 = smax[2], m3 = smax[3];
    float i0 = sinv[0], i1 = sinv[1], i2 = sinv[2], i3 = sinv[3];
    float a0 = adr[n * NH + 0], a1 = adr[n * NH + 1];
    float a2 = adr[n * NH + 2], a3 = adr[n * NH + 3];
    float acc0 = 0.f, acc1 = 0.f, acc2 = 0.f, acc3 = 0.f;

    for (int cb = 0; cb < deg; cb += 128) {
        int cl = deg - cb; if (cl > 128) cl = 128;
        if (t < cl) {
            int s = csr_src[start + cb + t];
            float4 av = *(const float4*)(asr + s * NH);
            float v0 = av.x + a0; v0 = v0 >= 0.f ? v0 : 0.2f * v0;
            float v1 = av.y + a1; v1 = v1 >= 0.f ? v1 : 0.2f * v1;
            float v2 = av.z + a2; v2 = v2 >= 0.f ? v2 : 0.2f * v2;
            float v3 = av.w + a3; v3 = v3 >= 0.f ? v3 : 0.2f * v3;
            lal[t][0] = __expf(v0 - m0) * i0;
            lal[t][1] = __expf(v1 - m1) * i1;
            lal[t][2] = __expf(v2 - m2) * i2;
            lal[t][3] = __expf(v3 - m3) * i3;
            lsrc[t] = s;
        }
        __syncthreads();
#pragma unroll 4
        for (int j = 0; j < cl; ++j) {
            float xv = X[(size_t)lsrc[j] * D + t];
            float4 w = *(const float4*)lal[j];
            acc0 += w.x * xv;
            acc1 += w.y * xv;
            acc2 += w.z * xv;
            acc3 += w.w * xv;
        }
        __syncthreads();
    }

    size_t base = (size_t)n * HC + t;
    unsigned short hh, ll;
    fsplit(acc0, &hh, &ll); aggh[base + 0 * D] = hh; aggl[base + 0 * D] = ll;
    fsplit(acc1, &hh, &ll); aggh[base + 1 * D] = hh; aggl[base + 1 * D] = ll;
    fsplit(acc2, &hh, &ll); aggh[base + 2 * D] = hh; aggl[base + 2 * D] = ll;
    fsplit(acc3, &hh, &ll); aggh[base + 3 * D] = hh; aggl[base + 3 * D] = ll;
}

// ---- K4: MFMA split-bf16 GEMM: out = agg @ Bt^T + bias (+gelu) ----
// grid (NN/16, 128/64); 1 wave/block; wave: 16 rows x 64 cols
__global__ __launch_bounds__(64)
void gemm_mfma(const unsigned short* __restrict__ Ah, const unsigned short* __restrict__ Al,
               const unsigned short* __restrict__ Bth, const unsigned short* __restrict__ Btl,
               const float* __restrict__ bias, float* __restrict__ Out, int do_gelu) {
    int lane = threadIdx.x;
    int m0 = blockIdx.x * 16;
    int n0 = blockIdx.y * 64;
    int r = lane & 15;
    int g = lane >> 4;

    const bf16x8* ah = (const bf16x8*)(Ah + (size_t)(m0 + r) * HC + g * 8);
    const bf16x8* al = (const bf16x8*)(Al + (size_t)(m0 + r) * HC + g * 8);
    const bf16x8* bh0 = (const bf16x8*)(Bth + (size_t)(n0 + 0 * 16 + r) * HC + g * 8);
    const bf16x8* bh1 = (const bf16x8*)(Bth + (size_t)(n0 + 1 * 16 + r) * HC + g * 8);
    const bf16x8* bh2 = (const bf16x8*)(Bth + (size_t)(n0 + 2 * 16 + r) * HC + g * 8);
    const bf16x8* bh3 = (const bf16x8*)(Bth + (size_t)(n0 + 3 * 16 + r) * HC + g * 8);
    const bf16x8* bl0 = (const bf16x8*)(Btl + (size_t)(n0 + 0 * 16 + r) * HC + g * 8);
    const bf16x8* bl1 = (const bf16x8*)(Btl + (size_t)(n0 + 1 * 16 + r) * HC + g * 8);
    const bf16x8* bl2 = (const bf16x8*)(Btl + (size_t)(n0 + 2 * 16 + r) * HC + g * 8);
    const bf16x8* bl3 = (const bf16x8*)(Btl + (size_t)(n0 + 3 * 16 + r) * HC + g * 8);

    f32x4 acc[4];
#pragma unroll
    for (int q = 0; q < 4; ++q) acc[q] = (f32x4){0.f, 0.f, 0.f, 0.f};

#pragma unroll 2
    for (int ks = 0; ks < HC / 32; ++ks) {
        bf16x8 a_h = ah[ks * 4];
        bf16x8 a_l = al[ks * 4];
        bf16x8 b;
        b = bh0[ks * 4];
        acc[0] = __builtin_amdgcn_mfma_f32_16x16x32_bf16(a_h, b, acc[0], 0, 0, 0);
        acc[0] = __builtin_amdgcn_mfma_f32_16x16x32_bf16(a_l, b, acc[0], 0, 0, 0);
        b = bl0[ks * 4];
        acc[0] = __builtin_amdgcn_mfma_f32_16x16x32_bf16(a_h, b, acc[0], 0, 0, 0);
        b = bh1[ks * 4];
        acc[1] = __builtin_amdgcn_mfma_f32_16x16x32_bf16(a_h, b, acc[1], 0, 0, 0);
        acc[1] = __builtin_amdgcn_mfma_f32_16x16x32_bf16(a_l, b, acc[1], 0, 0, 0);
        b = bl1[ks * 4];
        acc[1] = __builtin_amdgcn_mfma_f32_16x16x32_bf16(a_h, b, acc[1], 0, 0, 0);
        b = bh2[ks * 4];
        acc[2] = __builtin_amdgcn_mfma_f32_16x16x32_bf16(a_h, b, acc[2], 0, 0, 0);
        acc[2] = __builtin_amdgcn_mfma_f32_16x16x32_bf16(a_l, b, acc[2], 0, 0, 0);
        b = bl2[ks * 4];
        acc[2] = __builtin_amdgcn_mfma_f32_16x16x32_bf16(a_h, b, acc[2], 0, 0, 0);
        b = bh3[ks * 4];
        acc[3] = __builtin_amdgcn_mfma_f32_16x16x32_bf16(a_h, b, acc[3], 0, 0, 0);
        acc[3] = __builtin_amdgcn_mfma_f32_16x16x32_bf16(a_l, b, acc[3], 0, 0, 0);
        b = bl3[ks * 4];
        acc[3] = __builtin_amdgcn_mfma_f32_16x16x32_bf16(a_h, b, acc[3], 0, 0, 0);
    }

    // C/D: row = (lane>>4)*4 + reg, col = lane&15  (m89-verified)
#pragma unroll
    for (int q = 0; q < 4; ++q) {
#pragma unroll
        for (int i = 0; i < 4; ++i) {
            int row = m0 + g * 4 + i;
            int col = n0 + q * 16 + r;
            float v = acc[q][i] + bias[col];
            if (do_gelu) {
                float u = 0.7978845608028654f * (v + 0.044715f * v * v * v);
                v = 0.5f * v * (1.f + tanhf(u));
            }
            Out[(size_t)row * D + col] = v;
        }
    }
}

// ---- K5: pool agg3 over nodes -> p512 (hi+lo reconstructed) ----
__global__ __launch_bounds__(512)
void pool512(const unsigned short* __restrict__ Ah, const unsigned short* __restrict__ Al,
             float* __restrict__ p) {
    int t = threadIdx.x;
    int chunk = (NN + gridDim.x - 1) / gridDim.x;
    int n0 = blockIdx.x * chunk;
    int n1 = n0 + chunk; if (n1 > NN) n1 = NN;
    float acc = 0.f;
    for (int n = n0; n < n1; ++n)
        acc += bf2f(Ah[(size_t)n * HC + t]) + bf2f(Al[(size_t)n * HC + t]);
    atomicAdd(p + t, acc);
}

// ---- K6: logits = ((p512/NN) @ B3 + bias3) @ Wc + bc ; one block ----
__global__ __launch_bounds__(128)
void final_head(const float* __restrict__ p512, const float* __restrict__ W3,
                const float* __restrict__ bias3, const float* __restrict__ Wc,
                const float* __restrict__ bc, float* __restrict__ out) {
    __shared__ float t128[128];
    int t = threadIdx.x;
    float acc = bias3[t];
    const float inv = 1.0f / NN;
#pragma unroll 4
    for (int j = 0; j < HC; ++j)
        acc += p512[j] * inv * W3[(size_t)(j & 127) * HC + (j >> 7) * C + t];
    t128[t] = acc;
    __syncthreads();
    if (t < NCLS) {
        float o = bc[t];
#pragma unroll 4
        for (int c = 0; c < 128; ++c) o += t128[c] * Wc[c * NCLS + t];
        out[t] = o;
    }
}

extern "C" void kernel_launch(void* const* d_in, const int* in_sizes, int n_in,
                              void* d_out, int out_size, void* d_ws, size_t ws_size,
                              hipStream_t stream) {
    const int*   feats = (const int*)d_in[0];
    const int*   edges = (const int*)d_in[1];
    const float* emb   = (const float*)d_in[2];
    const float* W     = (const float*)d_in[3];
    const float* asrcW = (const float*)d_in[4];
    const float* adstW = (const float*)d_in[5];
    const float* bias  = (const float*)d_in[6];
    const float* Wc    = (const float*)d_in[7];
    const float* bc    = (const float*)d_in[8];
    float* out = (float*)d_out;

    const int* srcp = edges;
    const int* dstp = edges + NE;

    char* ws = (char*)d_ws;
    size_t off = 0;
    unsigned short* aggh = (unsigned short*)(ws + off); off += (size_t)NN * HC * 2;  // 10.24 MB
    unsigned short* aggl = (unsigned short*)(ws + off); off += (size_t)NN * HC * 2;  // 10.24 MB
    float* xb0    = (float*)(ws + off); off += (size_t)NN * D * 4;    // 5.12 MB
    float* xb1    = (float*)(ws + off); off += (size_t)NN * D * 4;    // 5.12 MB
    float* asrc   = (float*)(ws + off); off += (size_t)NN * NH * 4;
    float* adst   = (float*)(ws + off); off += (size_t)NN * NH * 4;
    int*   deg    = (int*)(ws + off);   off += (size_t)NN * 4;
    int*   rowst  = (int*)(ws + off);   off += (size_t)NN * 4;
    int*   cursor = (int*)(ws + off);   off += (size_t)NN * 4;
    int*   csrsrc = (int*)(ws + off);   off += (size_t)NE * 4;        // 0.64 MB
    float* wsrcb  = (float*)(ws + off); off += (size_t)NL * NH * D * 4;
    float* wdstb  = (float*)(ws + off); off += (size_t)NL * NH * D * 4;
    unsigned short* Bth = (unsigned short*)(ws + off); off += (size_t)2 * 128 * HC * 2; // 256 KB
    unsigned short* Btl = (unsigned short*)(ws + off); off += (size_t)2 * 128 * HC * 2;
    float* p512   = (float*)(ws + off); off += HC * 4;

    // ---- build CSR (dst-sorted) + fold W into attention vectors + split W ----
    hipMemsetAsync(deg, 0, (size_t)NN * 4, stream);
    hist<<<(NE + 255) / 256, 256, 0, stream>>>(dstp, deg);
    scan_deg<<<1, SCAN_T, 0, stream>>>(deg, rowst, cursor);
    scatter<<<(NE + 255) / 256, 256, 0, stream>>>(srcp, dstp, cursor, csrsrc);
    prep_att<<<NL * NH * 2, 128, 0, stream>>>(W, asrcW, adstW, wsrcb, wdstb);
    prep_w<<<2 * 128, 512, 0, stream>>>(W, Bth, Btl);

    atom_encoder<<<NN, 128, 0, stream>>>(feats, emb, xb0);

    float* xin = xb0;
    float* xout = xb1;
    for (int l = 0; l < 2; ++l) {
        alphas2<<<NN / 4, 256, 0, stream>>>(xin, wsrcb + (size_t)l * NH * D,
                                            wdstb + (size_t)l * NH * D, asrc, adst);
        gat_agg<<<NN, 128, 0, stream>>>(csrsrc, rowst, deg, asrc, adst, xin, aggh, aggl);
        gemm_mfma<<<dim3(NN / 16, 2), 64, 0, stream>>>(
            aggh, aggl, Bth + (size_t)l * 128 * HC, Btl + (size_t)l * 128 * HC,
            bias + (size_t)l * D, xout, 1);
        float* tmp = xin; xin = xout; xout = tmp;
    }

    // layer 3: attention+agg, then pool in agg-space (GEMM commuted past the mean)
    alphas2<<<NN / 4, 256, 0, stream>>>(xin, wsrcb + (size_t)2 * NH * D,
                                        wdstb + (size_t)2 * NH * D, asrc, adst);
    gat_agg<<<NN, 128, 0, stream>>>(csrsrc, rowst, deg, asrc, adst, xin, aggh, aggl);
    hipMemsetAsync(p512, 0, HC * 4, stream);
    pool512<<<100, 512, 0, stream>>>(aggh, aggl, p512);
    final_head<<<1, 128, 0, stream>>>(p512, W + (size_t)2 * D * HC,
                                      bias + (size_t)2 * D, Wc, bc, out);
}

// Round 7
// 320.129 us; speedup vs baseline: 3.9987x; 1.0511x over previous
//
#include <hip/hip_runtime.h>
#include <hip/hip_bf16.h>
#include <math.h>

#define NN 10000      // nodes
#define NE 160000     // edges
#define NF 9          // atom features
#define VOCAB 128
#define D 128
#define NH 4          // heads
#define C 128
#define HC 512        // NH*C
#define NCLS 10
#define NL 3

#define NEG_BIG (-1e30f)   // finite -inf substitute: avoids (-inf)-(-inf)=NaN in combines

typedef __attribute__((ext_vector_type(8))) short bf16x8;
typedef __attribute__((ext_vector_type(4))) float f32x4;

__device__ __forceinline__ unsigned short f2bf(float f) {
    unsigned u = __float_as_uint(f);
    unsigned r = ((u >> 16) & 1u) + 0x7FFFu;
    return (unsigned short)((u + r) >> 16);
}
__device__ __forceinline__ float bf2f(unsigned short h) {
    return __uint_as_float(((unsigned)h) << 16);
}

// ---- K0: atom encoder: x[n,d] = sum_f emb[f, feat[n,f], d] ----
__global__ __launch_bounds__(128)
void atom_encoder(const int* __restrict__ feats, const float* __restrict__ emb,
                  float* __restrict__ x) {
    int n = blockIdx.x;
    int d = threadIdx.x;
    __shared__ int f[NF];
    if (threadIdx.x < NF) f[threadIdx.x] = feats[n * NF + threadIdx.x];
    __syncthreads();
    float acc = 0.f;
#pragma unroll
    for (int i = 0; i < NF; ++i)
        acc += emb[(i * VOCAB + f[i]) * D + d];
    x[n * D + d] = acc;
}

// ---- CSR build: histogram of dst ----
__global__ __launch_bounds__(256)
void hist(const int* __restrict__ dst, int* __restrict__ deg) {
    int e = blockIdx.x * 256 + threadIdx.x;
    if (e < NE) atomicAdd(&deg[dst[e]], 1);
}

// ---- CSR build: one-block exclusive scan of deg[NN] -> rowstart, cursor ----
#define SCAN_T 1024
#define SCAN_PER ((NN + SCAN_T - 1) / SCAN_T)   // 10
__global__ __launch_bounds__(SCAN_T)
void scan_deg(const int* __restrict__ deg, int* __restrict__ rowstart,
              int* __restrict__ cursor) {
    __shared__ int part[SCAN_T];
    int t = threadIdx.x;
    int base = t * SCAN_PER;
    int vals[SCAN_PER];
    int loc = 0;
#pragma unroll
    for (int i = 0; i < SCAN_PER; ++i) {
        int idx = base + i;
        int v = (idx < NN) ? deg[idx] : 0;
        vals[i] = v;
        loc += v;
    }
    part[t] = loc;
    __syncthreads();
    for (int off = 1; off < SCAN_T; off <<= 1) {
        int y = (t >= off) ? part[t - off] : 0;
        __syncthreads();
        part[t] += y;
        __syncthreads();
    }
    int run = part[t] - loc;   // exclusive prefix
#pragma unroll
    for (int i = 0; i < SCAN_PER; ++i) {
        int idx = base + i;
        if (idx < NN) { rowstart[idx] = run; cursor[idx] = run; }
        run += vals[i];
    }
}

// ---- CSR build: scatter src sorted by dst ----
__global__ __launch_bounds__(256)
void scatter(const int* __restrict__ src, const int* __restrict__ dst,
             int* __restrict__ cursor, int* __restrict__ csr_src) {
    int e = blockIdx.x * 256 + threadIdx.x;
    if (e < NE) {
        int p = atomicAdd(&cursor[dst[e]], 1);
        csr_src[p] = src[e];
    }
}

// ---- P0: wsrc[l][h] = W_l,h @ a_s[l,h]; wdst likewise (24 blocks) ----
__global__ __launch_bounds__(128)
void prep_att(const float* __restrict__ W, const float* __restrict__ as_,
              const float* __restrict__ ad_, float* __restrict__ wsrc,
              float* __restrict__ wdst) {
    int l = blockIdx.x >> 3;
    int r = blockIdx.x & 7;
    int h = r >> 1;
    int side = r & 1;
    int k = threadIdx.x;
    const float* av = (side ? ad_ : as_) + (size_t)(l * NH + h) * C;
    const float* wrow = W + (size_t)l * D * HC + (size_t)k * HC + h * C;
    float acc = 0.f;
#pragma unroll 4
    for (int c = 0; c < C; ++c) acc += wrow[c] * av[c];
    float* o = (side ? wdst : wsrc) + (size_t)(l * NH + h) * D + k;
    *o = acc;
}

// ---- P1: W (layers 0,1) -> Bt[l][c][j], j = d*4 + h (d-major), bf16 hi/lo ----
__global__ __launch_bounds__(512)
void prep_w(const float* __restrict__ W, unsigned short* __restrict__ Bth,
            unsigned short* __restrict__ Btl) {
    int l = blockIdx.x >> 7;
    int c = blockIdx.x & 127;
    int j = threadIdx.x;
    float v = W[(size_t)l * D * HC + (size_t)(j >> 2) * HC + (j & 3) * C + c];
    unsigned short h = f2bf(v);
    unsigned short lo = f2bf(v - bf2f(h));
    size_t o = (size_t)(l * 128 + c) * HC + j;
    Bth[o] = h;
    Btl[o] = lo;
}

// ---- P2: M[k][j] = sum_c W3perm[j][c]*Wc[c][k]; b10; zero p512 ----
__global__ __launch_bounds__(512)
void prep_head(const float* __restrict__ W3, const float* __restrict__ Wc,
               const float* __restrict__ bias3, const float* __restrict__ bc,
               float* __restrict__ M, float* __restrict__ b10,
               float* __restrict__ p512) {
    int k = blockIdx.x;
    int j = threadIdx.x;
    const float* wrow = W3 + (size_t)(j >> 2) * HC + (j & 3) * C;
    float acc = 0.f;
#pragma unroll 4
    for (int c = 0; c < C; ++c) acc += wrow[c] * Wc[c * NCLS + k];
    M[(size_t)k * HC + j] = acc;
    if (k == 0) p512[j] = 0.f;
    if (j == 0) {
        float b = bc[k];
        for (int c = 0; c < C; ++c) b += bias3[c] * Wc[c * NCLS + k];
        b10[k] = b;
    }
}

// ---- K2: alpha_src/dst[n,h] = x[n] . wvec[h]  (4 nodes per 256-thr block) ----
__global__ __launch_bounds__(256)
void alphas2(const float* __restrict__ X, const float* __restrict__ wsrc,
             const float* __restrict__ wdst, float* __restrict__ asrc,
             float* __restrict__ adst) {
    int n = blockIdx.x * 4 + (threadIdx.x >> 6);
    int lane = threadIdx.x & 63;
    float x0 = X[n * D + lane], x1 = X[n * D + lane + 64];
#pragma unroll
    for (int h = 0; h < NH; ++h) {
        float s = x0 * wsrc[h * D + lane] + x1 * wsrc[h * D + lane + 64];
        float d = x0 * wdst[h * D + lane] + x1 * wdst[h * D + lane + 64];
#pragma unroll
        for (int off = 32; off; off >>= 1) {
            s += __shfl_down(s, off);
            d += __shfl_down(d, off);
        }
        if (lane == 0) { asrc[n * NH + h] = s; adst[n * NH + h] = d; }
    }
}

// ---- K3: fused per-dst online-softmax + aggregation -> agg bf16 hi/lo ----
// layout: agg[n][j], j = d*4 + h  (thread t=d packs 4 heads into 8B stores)
__global__ __launch_bounds__(128)
void gat_agg(const int* __restrict__ csr_src, const int* __restrict__ rowstart,
             const int* __restrict__ degA, const float* __restrict__ asr,
             const float* __restrict__ adr, const float* __restrict__ X,
             unsigned* __restrict__ aggh, unsigned* __restrict__ aggl) {
    int n = blockIdx.x;
    int t = threadIdx.x;
    int deg = degA[n];
    int start = rowstart[n];

    __shared__ float redm[2][NH];
    __shared__ float reds[2][NH];
    __shared__ float lal[128][NH];
    __shared__ int lsrc[128];

    float a0 = adr[n * NH + 0], a1 = adr[n * NH + 1];
    float a2 = adr[n * NH + 2], a3 = adr[n * NH + 3];

    // ---- phase A: single-pass online (m, s) per head, all 128 threads ----
    // NEG_BIG (finite) identity: (-inf)-(-inf)=NaN killed the -INFINITY version
    float m[NH] = {NEG_BIG, NEG_BIG, NEG_BIG, NEG_BIG};
    float s[NH] = {0.f, 0.f, 0.f, 0.f};
    for (int j = t; j < deg; j += 128) {
        int sn = csr_src[start + j];
        float4 av = *(const float4*)(asr + sn * NH);
        float v[NH];
        v[0] = av.x + a0; v[0] = v[0] >= 0.f ? v[0] : 0.2f * v[0];
        v[1] = av.y + a1; v[1] = v[1] >= 0.f ? v[1] : 0.2f * v[1];
        v[2] = av.z + a2; v[2] = v[2] >= 0.f ? v[2] : 0.2f * v[2];
        v[3] = av.w + a3; v[3] = v[3] >= 0.f ? v[3] : 0.2f * v[3];
#pragma unroll
        for (int h = 0; h < NH; ++h) {
            float nm = fmaxf(m[h], v[h]);
            s[h] = s[h] * __expf(m[h] - nm) + __expf(v[h] - nm);
            m[h] = nm;
        }
    }
#pragma unroll
    for (int off = 32; off; off >>= 1) {
#pragma unroll
        for (int h = 0; h < NH; ++h) {
            float om = __shfl_xor(m[h], off);
            float os = __shfl_xor(s[h], off);
            float nm = fmaxf(m[h], om);
            s[h] = s[h] * __expf(m[h] - nm) + os * __expf(om - nm);
            m[h] = nm;
        }
    }
    if ((t & 63) == 0) {
        int w = t >> 6;
#pragma unroll
        for (int h = 0; h < NH; ++h) { redm[w][h] = m[h]; reds[w][h] = s[h]; }
    }
    __syncthreads();
    float fm[NH], fi[NH];
#pragma unroll
    for (int h = 0; h < NH; ++h) {
        float m0 = redm[0][h], m1 = redm[1][h];
        float nm = fmaxf(m0, m1);
        float sv = reds[0][h] * __expf(m0 - nm) + reds[1][h] * __expf(m1 - nm);
        fm[h] = nm;
        fi[h] = 0.25f / (sv + 1e-16f);   // fold head-mean 1/NH
    }

    // ---- phase B: thread t owns channel d=t; 4 head accumulators ----
    float acc0 = 0.f, acc1 = 0.f, acc2 = 0.f, acc3 = 0.f;
    for (int cb = 0; cb < deg; cb += 128) {
        int cl = deg - cb; if (cl > 128) cl = 128;
        if (t < cl) {
            int sn = csr_src[start + cb + t];
            float4 av = *(const float4*)(asr + sn * NH);
            float v0 = av.x + a0; v0 = v0 >= 0.f ? v0 : 0.2f * v0;
            float v1 = av.y + a1; v1 = v1 >= 0.f ? v1 : 0.2f * v1;
            float v2 = av.z + a2; v2 = v2 >= 0.f ? v2 : 0.2f * v2;
            float v3 = av.w + a3; v3 = v3 >= 0.f ? v3 : 0.2f * v3;
            lal[t][0] = __expf(v0 - fm[0]) * fi[0];
            lal[t][1] = __expf(v1 - fm[1]) * fi[1];
            lal[t][2] = __expf(v2 - fm[2]) * fi[2];
            lal[t][3] = __expf(v3 - fm[3]) * fi[3];
            lsrc[t] = sn;
        }
        __syncthreads();
#pragma unroll 4
        for (int j = 0; j < cl; ++j) {
            float xv = X[(size_t)lsrc[j] * D + t];
            float4 w = *(const float4*)lal[j];
            acc0 += w.x * xv;
            acc1 += w.y * xv;
            acc2 += w.z * xv;
            acc3 += w.w * xv;
        }
        __syncthreads();
    }

    // packed stores: j = t*4 + h -> two dwords per buffer
    unsigned short h0 = f2bf(acc0), h1 = f2bf(acc1), h2 = f2bf(acc2), h3 = f2bf(acc3);
    unsigned short l0 = f2bf(acc0 - bf2f(h0)), l1 = f2bf(acc1 - bf2f(h1));
    unsigned short l2 = f2bf(acc2 - bf2f(h2)), l3 = f2bf(acc3 - bf2f(h3));
    size_t base = ((size_t)n * HC + t * 4) >> 1;   // dword index
    uint2 uh = make_uint2((unsigned)h0 | ((unsigned)h1 << 16),
                          (unsigned)h2 | ((unsigned)h3 << 16));
    uint2 ul = make_uint2((unsigned)l0 | ((unsigned)l1 << 16),
                          (unsigned)l2 | ((unsigned)l3 << 16));
    *(uint2*)(aggh + base) = uh;
    *(uint2*)(aggl + base) = ul;
}

// ---- K4: MFMA split-bf16 GEMM: out = agg @ Bt^T + bias (+gelu) ----
// grid (NN/16, 128/64); 1 wave/block; wave: 16 rows x 64 cols
__global__ __launch_bounds__(64)
void gemm_mfma(const unsigned short* __restrict__ Ah, const unsigned short* __restrict__ Al,
               const unsigned short* __restrict__ Bth, const unsigned short* __restrict__ Btl,
               const float* __restrict__ bias, float* __restrict__ Out, int do_gelu) {
    int lane = threadIdx.x;
    int m0 = blockIdx.x * 16;
    int n0 = blockIdx.y * 64;
    int r = lane & 15;
    int g = lane >> 4;

    const bf16x8* ah = (const bf16x8*)(Ah + (size_t)(m0 + r) * HC + g * 8);
    const bf16x8* al = (const bf16x8*)(Al + (size_t)(m0 + r) * HC + g * 8);
    const bf16x8* bh0 = (const bf16x8*)(Bth + (size_t)(n0 + 0 * 16 + r) * HC + g * 8);
    const bf16x8* bh1 = (const bf16x8*)(Bth + (size_t)(n0 + 1 * 16 + r) * HC + g * 8);
    const bf16x8* bh2 = (const bf16x8*)(Bth + (size_t)(n0 + 2 * 16 + r) * HC + g * 8);
    const bf16x8* bh3 = (const bf16x8*)(Bth + (size_t)(n0 + 3 * 16 + r) * HC + g * 8);
    const bf16x8* bl0 = (const bf16x8*)(Btl + (size_t)(n0 + 0 * 16 + r) * HC + g * 8);
    const bf16x8* bl1 = (const bf16x8*)(Btl + (size_t)(n0 + 1 * 16 + r) * HC + g * 8);
    const bf16x8* bl2 = (const bf16x8*)(Btl + (size_t)(n0 + 2 * 16 + r) * HC + g * 8);
    const bf16x8* bl3 = (const bf16x8*)(Btl + (size_t)(n0 + 3 * 16 + r) * HC + g * 8);

    f32x4 acc[4];
#pragma unroll
    for (int q = 0; q < 4; ++q) acc[q] = (f32x4){0.f, 0.f, 0.f, 0.f};

#pragma unroll 2
    for (int ks = 0; ks < HC / 32; ++ks) {
        bf16x8 a_h = ah[ks * 4];
        bf16x8 a_l = al[ks * 4];
        bf16x8 b;
        b = bh0[ks * 4];
        acc[0] = __builtin_amdgcn_mfma_f32_16x16x32_bf16(a_h, b, acc[0], 0, 0, 0);
        acc[0] = __builtin_amdgcn_mfma_f32_16x16x32_bf16(a_l, b, acc[0], 0, 0, 0);
        b = bl0[ks * 4];
        acc[0] = __builtin_amdgcn_mfma_f32_16x16x32_bf16(a_h, b, acc[0], 0, 0, 0);
        b = bh1[ks * 4];
        acc[1] = __builtin_amdgcn_mfma_f32_16x16x32_bf16(a_h, b, acc[1], 0, 0, 0);
        acc[1] = __builtin_amdgcn_mfma_f32_16x16x32_bf16(a_l, b, acc[1], 0, 0, 0);
        b = bl1[ks * 4];
        acc[1] = __builtin_amdgcn_mfma_f32_16x16x32_bf16(a_h, b, acc[1], 0, 0, 0);
        b = bh2[ks * 4];
        acc[2] = __builtin_amdgcn_mfma_f32_16x16x32_bf16(a_h, b, acc[2], 0, 0, 0);
        acc[2] = __builtin_amdgcn_mfma_f32_16x16x32_bf16(a_l, b, acc[2], 0, 0, 0);
        b = bl2[ks * 4];
        acc[2] = __builtin_amdgcn_mfma_f32_16x16x32_bf16(a_h, b, acc[2], 0, 0, 0);
        b = bh3[ks * 4];
        acc[3] = __builtin_amdgcn_mfma_f32_16x16x32_bf16(a_h, b, acc[3], 0, 0, 0);
        acc[3] = __builtin_amdgcn_mfma_f32_16x16x32_bf16(a_l, b, acc[3], 0, 0, 0);
        b = bl3[ks * 4];
        acc[3] = __builtin_amdgcn_mfma_f32_16x16x32_bf16(a_h, b, acc[3], 0, 0, 0);
    }

    // C/D: row = (lane>>4)*4 + reg, col = lane&15  (m89-verified)
#pragma unroll
    for (int q = 0; q < 4; ++q) {
#pragma unroll
        for (int i = 0; i < 4; ++i) {
            int row = m0 + g * 4 + i;
            int col = n0 + q * 16 + r;
            float v = acc[q][i] + bias[col];
            if (do_gelu) {
                float u = 0.7978845608028654f * (v + 0.044715f * v * v * v);
                v = 0.5f * v * (1.f + tanhf(u));
            }
            Out[(size_t)row * D + col] = v;
        }
    }
}

// ---- K5: pool agg3 over nodes -> p512 (hi+lo reconstructed) ----
__global__ __launch_bounds__(512)
void pool512(const unsigned short* __restrict__ Ah, const unsigned short* __restrict__ Al,
             float* __restrict__ p) {
    int t = threadIdx.x;
    int chunk = (NN + gridDim.x - 1) / gridDim.x;
    int n0 = blockIdx.x * chunk;
    int n1 = n0 + chunk; if (n1 > NN) n1 = NN;
    float acc = 0.f;
    for (int n = n0; n < n1; ++n)
        acc += bf2f(Ah[(size_t)n * HC + t]) + bf2f(Al[(size_t)n * HC + t]);
    atomicAdd(p + t, acc);
}

// ---- K6: out[k] = b10[k] + (1/NN) * p512 . M[k,:] ; 10 waves ----
__global__ __launch_bounds__(640)
void final10(const float* __restrict__ p512, const float* __restrict__ M,
             const float* __restrict__ b10, float* __restrict__ out) {
    int k = threadIdx.x >> 6;
    int lane = threadIdx.x & 63;
    float acc = 0.f;
#pragma unroll
    for (int i = 0; i < HC / 64; ++i) {
        int j = lane + i * 64;
        acc += p512[j] * M[(size_t)k * HC + j];
    }
#pragma unroll
    for (int off = 32; off; off >>= 1) acc += __shfl_down(acc, off);
    if (lane == 0) out[k] = b10[k] + acc * (1.0f / NN);
}

extern "C" void kernel_launch(void* const* d_in, const int* in_sizes, int n_in,
                              void* d_out, int out_size, void* d_ws, size_t ws_size,
                              hipStream_t stream) {
    const int*   feats = (const int*)d_in[0];
    const int*   edges = (const int*)d_in[1];
    const float* emb   = (const float*)d_in[2];
    const float* W     = (const float*)d_in[3];
    const float* asrcW = (const float*)d_in[4];
    const float* adstW = (const float*)d_in[5];
    const float* bias  = (const float*)d_in[6];
    const float* Wc    = (const float*)d_in[7];
    const float* bc    = (const float*)d_in[8];
    float* out = (float*)d_out;

    const int* srcp = edges;
    const int* dstp = edges + NE;

    char* ws = (char*)d_ws;
    size_t off = 0;
    unsigned short* aggh = (unsigned short*)(ws + off); off += (size_t)NN * HC * 2;  // 10.24 MB
    unsigned short* aggl = (unsigned short*)(ws + off); off += (size_t)NN * HC * 2;  // 10.24 MB
    float* xb0    = (float*)(ws + off); off += (size_t)NN * D * 4;    // 5.12 MB
    float* xb1    = (float*)(ws + off); off += (size_t)NN * D * 4;    // 5.12 MB
    float* asrc   = (float*)(ws + off); off += (size_t)NN * NH * 4;
    float* adst   = (float*)(ws + off); off += (size_t)NN * NH * 4;
    int*   deg    = (int*)(ws + off);   off += (size_t)NN * 4;
    int*   rowst  = (int*)(ws + off);   off += (size_t)NN * 4;
    int*   cursor = (int*)(ws + off);   off += (size_t)NN * 4;
    int*   csrsrc = (int*)(ws + off);   off += (size_t)NE * 4;        // 0.64 MB
    float* wsrcb  = (float*)(ws + off); off += (size_t)NL * NH * D * 4;
    float* wdstb  = (float*)(ws + off); off += (size_t)NL * NH * D * 4;
    unsigned short* Bth = (unsigned short*)(ws + off); off += (size_t)2 * 128 * HC * 2; // 128 KB
    unsigned short* Btl = (unsigned short*)(ws + off); off += (size_t)2 * 128 * HC * 2;
    float* Mhead  = (float*)(ws + off); off += (size_t)NCLS * HC * 4; // 20 KB
    float* b10    = (float*)(ws + off); off += NCLS * 4;
    float* p512   = (float*)(ws + off); off += HC * 4;

    // ---- prep: CSR + folded attention vectors + split W + head matrix ----
    hipMemsetAsync(deg, 0, (size_t)NN * 4, stream);
    hist<<<(NE + 255) / 256, 256, 0, stream>>>(dstp, deg);
    scan_deg<<<1, SCAN_T, 0, stream>>>(deg, rowst, cursor);
    scatter<<<(NE + 255) / 256, 256, 0, stream>>>(srcp, dstp, cursor, csrsrc);
    prep_att<<<NL * NH * 2, 128, 0, stream>>>(W, asrcW, adstW, wsrcb, wdstb);
    prep_w<<<2 * 128, 512, 0, stream>>>(W, Bth, Btl);
    prep_head<<<NCLS, 512, 0, stream>>>(W + (size_t)2 * D * HC, Wc,
                                        bias + (size_t)2 * D, bc, Mhead, b10, p512);

    atom_encoder<<<NN, 128, 0, stream>>>(feats, emb, xb0);

    float* xin = xb0;
    float* xout = xb1;
    for (int l = 0; l < 2; ++l) {
        alphas2<<<NN / 4, 256, 0, stream>>>(xin, wsrcb + (size_t)l * NH * D,
                                            wdstb + (size_t)l * NH * D, asrc, adst);
        gat_agg<<<NN, 128, 0, stream>>>(csrsrc, rowst, deg, asrc, adst, xin,
                                        (unsigned*)aggh, (unsigned*)aggl);
        gemm_mfma<<<dim3(NN / 16, 2), 64, 0, stream>>>(
            aggh, aggl, Bth + (size_t)l * 128 * HC, Btl + (size_t)l * 128 * HC,
            bias + (size_t)l * D, xout, 1);
        float* tmp = xin; xin = xout; xout = tmp;
    }

    // layer 3: attention+agg, then pool in agg-space (GEMM commuted past mean)
    alphas2<<<NN / 4, 256, 0, stream>>>(xin, wsrcb + (size_t)2 * NH * D,
                                        wdstb + (size_t)2 * NH * D, asrc, adst);
    gat_agg<<<NN, 128, 0, stream>>>(csrsrc, rowst, deg, asrc, adst, xin,
                                    (unsigned*)aggh, (unsigned*)aggl);
    pool512<<<100, 512, 0, stream>>>(aggh, aggl, p512);
    final10<<<1, 640, 0, stream>>>(p512, Mhead, b10, out);
}

// Round 9
// 296.734 us; speedup vs baseline: 4.3139x; 1.0788x over previous
//
#include <hip/hip_runtime.h>
#include <hip/hip_bf16.h>
#include <math.h>

#define NN 10000      // nodes
#define NE 160000     // edges
#define NF 9          // atom features
#define VOCAB 128
#define D 128
#define NH 4          // heads
#define C 128
#define HC 512        // NH*C
#define NCLS 10
#define NL 3

#define NEG_BIG (-1e30f)   // finite -inf substitute

typedef __attribute__((ext_vector_type(8))) short bf16x8;
typedef __attribute__((ext_vector_type(4))) float f32x4;

__device__ __forceinline__ unsigned short f2bf(float f) {
    unsigned u = __float_as_uint(f);
    unsigned r = ((u >> 16) & 1u) + 0x7FFFu;
    return (unsigned short)((u + r) >> 16);
}
__device__ __forceinline__ float bf2f(unsigned short h) {
    return __uint_as_float(((unsigned)h) << 16);
}

// ---- CSR build: histogram of dst ----
__global__ __launch_bounds__(256)
void hist(const int* __restrict__ dst, int* __restrict__ deg) {
    int e = blockIdx.x * 256 + threadIdx.x;
    if (e < NE) atomicAdd(&deg[dst[e]], 1);
}

// ---- CSR build: one-block exclusive scan of deg[NN] -> rowstart, cursor ----
#define SCAN_T 1024
#define SCAN_PER ((NN + SCAN_T - 1) / SCAN_T)   // 10
__global__ __launch_bounds__(SCAN_T)
void scan_deg(const int* __restrict__ deg, int* __restrict__ rowstart,
              int* __restrict__ cursor) {
    __shared__ int part[SCAN_T];
    int t = threadIdx.x;
    int base = t * SCAN_PER;
    int vals[SCAN_PER];
    int loc = 0;
#pragma unroll
    for (int i = 0; i < SCAN_PER; ++i) {
        int idx = base + i;
        int v = (idx < NN) ? deg[idx] : 0;
        vals[i] = v;
        loc += v;
    }
    part[t] = loc;
    __syncthreads();
    for (int off = 1; off < SCAN_T; off <<= 1) {
        int y = (t >= off) ? part[t - off] : 0;
        __syncthreads();
        part[t] += y;
        __syncthreads();
    }
    int run = part[t] - loc;   // exclusive prefix
#pragma unroll
    for (int i = 0; i < SCAN_PER; ++i) {
        int idx = base + i;
        if (idx < NN) { rowstart[idx] = run; cursor[idx] = run; }
        run += vals[i];
    }
}

// ---- CSR build: scatter src sorted by dst ----
__global__ __launch_bounds__(256)
void scatter(const int* __restrict__ src, const int* __restrict__ dst,
             int* __restrict__ cursor, int* __restrict__ csr_src) {
    int e = blockIdx.x * 256 + threadIdx.x;
    if (e < NE) {
        int p = atomicAdd(&cursor[dst[e]], 1);
        csr_src[p] = src[e];
    }
}

// ---- P: merged prep. blocks [0,24): att vecs; [24,280): W split; [280,290): head ----
__global__ __launch_bounds__(512)
void prep_all(const float* __restrict__ W, const float* __restrict__ as_,
              const float* __restrict__ ad_, const float* __restrict__ Wc,
              const float* __restrict__ biasA, const float* __restrict__ bc,
              float* __restrict__ wsrc, float* __restrict__ wdst,
              unsigned short* __restrict__ Bth, unsigned short* __restrict__ Btl,
              float* __restrict__ M, float* __restrict__ b10,
              float* __restrict__ p512) {
    int b = blockIdx.x;
    if (b < 24) {                       // prep_att: 128 active threads
        int k = threadIdx.x;
        if (k >= 128) return;
        int l = b >> 3;
        int r = b & 7;
        int h = r >> 1;
        int side = r & 1;
        const float* av = (side ? ad_ : as_) + (size_t)(l * NH + h) * C;
        const float* wrow = W + (size_t)l * D * HC + (size_t)k * HC + h * C;
        float acc = 0.f;
#pragma unroll 4
        for (int c = 0; c < C; ++c) acc += wrow[c] * av[c];
        float* o = (side ? wdst : wsrc) + (size_t)(l * NH + h) * D + k;
        *o = acc;
    } else if (b < 280) {               // prep_w: j = d*4+h d-major split
        int bb = b - 24;
        int l = bb >> 7;
        int c = bb & 127;
        int j = threadIdx.x;
        float v = W[(size_t)l * D * HC + (size_t)(j >> 2) * HC + (j & 3) * C + c];
        unsigned short h = f2bf(v);
        unsigned short lo = f2bf(v - bf2f(h));
        size_t o = (size_t)(l * 128 + c) * HC + j;
        Bth[o] = h;
        Btl[o] = lo;
    } else {                            // prep_head
        int k = b - 280;
        int j = threadIdx.x;
        const float* W3 = W + (size_t)2 * D * HC;
        const float* bias3 = biasA + (size_t)2 * D;
        const float* wrow = W3 + (size_t)(j >> 2) * HC + (j & 3) * C;
        float acc = 0.f;
#pragma unroll 4
        for (int c = 0; c < C; ++c) acc += wrow[c] * Wc[c * NCLS + k];
        M[(size_t)k * HC + j] = acc;
        if (k == 0) p512[j] = 0.f;
        if (j == 0) {
            float bsum = bc[k];
            for (int c = 0; c < C; ++c) bsum += bias3[c] * Wc[c * NCLS + k];
            b10[k] = bsum;
        }
    }
}

// ---- K0: atom encoder + layer-0 alphas fused (x in registers) ----
__global__ __launch_bounds__(128)
void atom_encoder_alpha(const int* __restrict__ feats, const float* __restrict__ emb,
                        const float* __restrict__ wsrc0, const float* __restrict__ wdst0,
                        float* __restrict__ x, float* __restrict__ asrc,
                        float* __restrict__ adst) {
    int n = blockIdx.x;
    int t = threadIdx.x;
    __shared__ int f[NF];
    __shared__ float part[2][8];
    if (t < NF) f[t] = feats[n * NF + t];
    __syncthreads();
    float acc = 0.f;
#pragma unroll
    for (int i = 0; i < NF; ++i)
        acc += emb[(i * VOCAB + f[i]) * D + t];
    x[n * D + t] = acc;

    // 8 dot-products: sum_t acc * w[h][t] for src(0..3) and dst(4..7)
    float dots[8];
#pragma unroll
    for (int h = 0; h < NH; ++h) {
        dots[h]     = acc * wsrc0[h * D + t];
        dots[4 + h] = acc * wdst0[h * D + t];
    }
#pragma unroll
    for (int off = 32; off; off >>= 1)
#pragma unroll
        for (int k = 0; k < 8; ++k) dots[k] += __shfl_down(dots[k], off);
    if ((t & 63) == 0) {
        int w = t >> 6;
#pragma unroll
        for (int k = 0; k < 8; ++k) part[w][k] = dots[k];
    }
    __syncthreads();
    if (t < 8) {
        float v = part[0][t] + part[1][t];
        if (t < 4) asrc[n * NH + t] = v;
        else       adst[n * NH + (t - 4)] = v;
    }
}

// ---- K2: alpha_src/dst[n,h] = x[n] . wvec[h]  (4 nodes per 256-thr block) ----
__global__ __launch_bounds__(256)
void alphas2(const float* __restrict__ X, const float* __restrict__ wsrc,
             const float* __restrict__ wdst, float* __restrict__ asrc,
             float* __restrict__ adst) {
    int n = blockIdx.x * 4 + (threadIdx.x >> 6);
    int lane = threadIdx.x & 63;
    float x0 = X[n * D + lane], x1 = X[n * D + lane + 64];
#pragma unroll
    for (int h = 0; h < NH; ++h) {
        float s = x0 * wsrc[h * D + lane] + x1 * wsrc[h * D + lane + 64];
        float d = x0 * wdst[h * D + lane] + x1 * wdst[h * D + lane + 64];
#pragma unroll
        for (int off = 32; off; off >>= 1) {
            s += __shfl_down(s, off);
            d += __shfl_down(d, off);
        }
        if (lane == 0) { asrc[n * NH + h] = s; adst[n * NH + h] = d; }
    }
}

// ---- K3: per-dst softmax (two-pass, cheap reductions) + aggregation ----
// layout: agg[n][j], j = d*4 + h  (thread t=d packs 4 heads into 8B stores)
__global__ __launch_bounds__(128)
void gat_agg(const int* __restrict__ csr_src, const int* __restrict__ rowstart,
             const int* __restrict__ degA, const float* __restrict__ asr,
             const float* __restrict__ adr, const float* __restrict__ X,
             unsigned* __restrict__ aggh, unsigned* __restrict__ aggl) {
    int n = blockIdx.x;
    int t = threadIdx.x;
    int deg = degA[n];
    int start = rowstart[n];

    __shared__ float smax[NH];
    __shared__ float sinv[NH];
    __shared__ float lal[128][NH];
    __shared__ int lsrc[128];

    // ---- phase A: per-head max then exp-sum, 32 lanes per head ----
    int h = t >> 5, i = t & 31;
    float ad_h = adr[n * NH + h];
    float mx = NEG_BIG;
    for (int j = i; j < deg; j += 32) {
        int s = csr_src[start + j];
        float v = asr[s * NH + h] + ad_h;
        v = v >= 0.f ? v : 0.2f * v;
        mx = fmaxf(mx, v);
    }
#pragma unroll
    for (int off = 16; off; off >>= 1) mx = fmaxf(mx, __shfl_xor(mx, off));
    if (i == 0) smax[h] = mx;
    __syncthreads();
    float m = smax[h];
    float ss = 0.f;
    for (int j = i; j < deg; j += 32) {
        int s = csr_src[start + j];
        float v = asr[s * NH + h] + ad_h;
        v = v >= 0.f ? v : 0.2f * v;
        ss += __expf(v - m);
    }
#pragma unroll
    for (int off = 16; off; off >>= 1) ss += __shfl_xor(ss, off);
    if (i == 0) sinv[h] = 0.25f / (ss + 1e-16f);   // fold head-mean 1/NH
    __syncthreads();

    // ---- phase B: thread t owns channel d=t; 4 head accumulators ----
    float fm0 = smax[0], fm1 = smax[1], fm2 = smax[2], fm3 = smax[3];
    float fi0 = sinv[0], fi1 = sinv[1], fi2 = sinv[2], fi3 = sinv[3];
    float a0 = adr[n * NH + 0], a1 = adr[n * NH + 1];
    float a2 = adr[n * NH + 2], a3 = adr[n * NH + 3];
    float acc0 = 0.f, acc1 = 0.f, acc2 = 0.f, acc3 = 0.f;

    for (int cb = 0; cb < deg; cb += 128) {
        int cl = deg - cb; if (cl > 128) cl = 128;
        if (t < cl) {
            int sn = csr_src[start + cb + t];
            float4 av = *(const float4*)(asr + sn * NH);
            float v0 = av.x + a0; v0 = v0 >= 0.f ? v0 : 0.2f * v0;
            float v1 = av.y + a1; v1 = v1 >= 0.f ? v1 : 0.2f * v1;
            float v2 = av.z + a2; v2 = v2 >= 0.f ? v2 : 0.2f * v2;
            float v3 = av.w + a3; v3 = v3 >= 0.f ? v3 : 0.2f * v3;
            lal[t][0] = __expf(v0 - fm0) * fi0;
            lal[t][1] = __expf(v1 - fm1) * fi1;
            lal[t][2] = __expf(v2 - fm2) * fi2;
            lal[t][3] = __expf(v3 - fm3) * fi3;
            lsrc[t] = sn;
        }
        __syncthreads();
#pragma unroll 4
        for (int j = 0; j < cl; ++j) {
            float xv = X[(size_t)lsrc[j] * D + t];
            float4 w = *(const float4*)lal[j];
            acc0 += w.x * xv;
            acc1 += w.y * xv;
            acc2 += w.z * xv;
            acc3 += w.w * xv;
        }
        __syncthreads();
    }

    // packed stores: j = t*4 + h -> two dwords per buffer
    unsigned short h0 = f2bf(acc0), h1 = f2bf(acc1), h2 = f2bf(acc2), h3 = f2bf(acc3);
    unsigned short l0 = f2bf(acc0 - bf2f(h0)), l1 = f2bf(acc1 - bf2f(h1));
    unsigned short l2 = f2bf(acc2 - bf2f(h2)), l3 = f2bf(acc3 - bf2f(h3));
    size_t base = ((size_t)n * HC + t * 4) >> 1;   // dword index
    uint2 uh = make_uint2((unsigned)h0 | ((unsigned)h1 << 16),
                          (unsigned)h2 | ((unsigned)h3 << 16));
    uint2 ul = make_uint2((unsigned)l0 | ((unsigned)l1 << 16),
                          (unsigned)l2 | ((unsigned)l3 << 16));
    *(uint2*)(aggh + base) = uh;
    *(uint2*)(aggl + base) = ul;
}

// ---- K4: MFMA split-bf16 GEMM: out = agg @ Bt^T + bias (+gelu) ----
// grid (NN/16, 128/64); 1 wave/block; wave: 16 rows x 64 cols
__global__ __launch_bounds__(64)
void gemm_mfma(const unsigned short* __restrict__ Ah, const unsigned short* __restrict__ Al,
               const unsigned short* __restrict__ Bth, const unsigned short* __restrict__ Btl,
               const float* __restrict__ bias, float* __restrict__ Out, int do_gelu) {
    int lane = threadIdx.x;
    int m0 = blockIdx.x * 16;
    int n0 = blockIdx.y * 64;
    int r = lane & 15;
    int g = lane >> 4;

    const bf16x8* ah = (const bf16x8*)(Ah + (size_t)(m0 + r) * HC + g * 8);
    const bf16x8* al = (const bf16x8*)(Al + (size_t)(m0 + r) * HC + g * 8);
    const bf16x8* bh0 = (const bf16x8*)(Bth + (size_t)(n0 + 0 * 16 + r) * HC + g * 8);
    const bf16x8* bh1 = (const bf16x8*)(Bth + (size_t)(n0 + 1 * 16 + r) * HC + g * 8);
    const bf16x8* bh2 = (const bf16x8*)(Bth + (size_t)(n0 + 2 * 16 + r) * HC + g * 8);
    const bf16x8* bh3 = (const bf16x8*)(Bth + (size_t)(n0 + 3 * 16 + r) * HC + g * 8);
    const bf16x8* bl0 = (const bf16x8*)(Btl + (size_t)(n0 + 0 * 16 + r) * HC + g * 8);
    const bf16x8* bl1 = (const bf16x8*)(Btl + (size_t)(n0 + 1 * 16 + r) * HC + g * 8);
    const bf16x8* bl2 = (const bf16x8*)(Btl + (size_t)(n0 + 2 * 16 + r) * HC + g * 8);
    const bf16x8* bl3 = (const bf16x8*)(Btl + (size_t)(n0 + 3 * 16 + r) * HC + g * 8);

    f32x4 acc[4];
#pragma unroll
    for (int q = 0; q < 4; ++q) acc[q] = (f32x4){0.f, 0.f, 0.f, 0.f};

#pragma unroll 2
    for (int ks = 0; ks < HC / 32; ++ks) {
        bf16x8 a_h = ah[ks * 4];
        bf16x8 a_l = al[ks * 4];
        bf16x8 b;
        b = bh0[ks * 4];
        acc[0] = __builtin_amdgcn_mfma_f32_16x16x32_bf16(a_h, b, acc[0], 0, 0, 0);
        acc[0] = __builtin_amdgcn_mfma_f32_16x16x32_bf16(a_l, b, acc[0], 0, 0, 0);
        b = bl0[ks * 4];
        acc[0] = __builtin_amdgcn_mfma_f32_16x16x32_bf16(a_h, b, acc[0], 0, 0, 0);
        b = bh1[ks * 4];
        acc[1] = __builtin_amdgcn_mfma_f32_16x16x32_bf16(a_h, b, acc[1], 0, 0, 0);
        acc[1] = __builtin_amdgcn_mfma_f32_16x16x32_bf16(a_l, b, acc[1], 0, 0, 0);
        b = bl1[ks * 4];
        acc[1] = __builtin_amdgcn_mfma_f32_16x16x32_bf16(a_h, b, acc[1], 0, 0, 0);
        b = bh2[ks * 4];
        acc[2] = __builtin_amdgcn_mfma_f32_16x16x32_bf16(a_h, b, acc[2], 0, 0, 0);
        acc[2] = __builtin_amdgcn_mfma_f32_16x16x32_bf16(a_l, b, acc[2], 0, 0, 0);
        b = bl2[ks * 4];
        acc[2] = __builtin_amdgcn_mfma_f32_16x16x32_bf16(a_h, b, acc[2], 0, 0, 0);
        b = bh3[ks * 4];
        acc[3] = __builtin_amdgcn_mfma_f32_16x16x32_bf16(a_h, b, acc[3], 0, 0, 0);
        acc[3] = __builtin_amdgcn_mfma_f32_16x16x32_bf16(a_l, b, acc[3], 0, 0, 0);
        b = bl3[ks * 4];
        acc[3] = __builtin_amdgcn_mfma_f32_16x16x32_bf16(a_h, b, acc[3], 0, 0, 0);
    }

    // C/D: row = (lane>>4)*4 + reg, col = lane&15  (m89-verified)
#pragma unroll
    for (int q = 0; q < 4; ++q) {
#pragma unroll
        for (int i = 0; i < 4; ++i) {
            int row = m0 + g * 4 + i;
            int col = n0 + q * 16 + r;
            float v = acc[q][i] + bias[col];
            if (do_gelu) {
                float u = 0.7978845608028654f * (v + 0.044715f * v * v * v);
                v = 0.5f * v * (1.f + tanhf(u));
            }
            Out[(size_t)row * D + col] = v;
        }
    }
}

// ---- K5: pool agg3 over nodes -> p512 (hi+lo reconstructed) ----
__global__ __launch_bounds__(512)
void pool512(const unsigned short* __restrict__ Ah, const unsigned short* __restrict__ Al,
             float* __restrict__ p) {
    int t = threadIdx.x;
    int chunk = (NN + gridDim.x - 1) / gridDim.x;
    int n0 = blockIdx.x * chunk;
    int n1 = n0 + chunk; if (n1 > NN) n1 = NN;
    float acc = 0.f;
    for (int n = n0; n < n1; ++n)
        acc += bf2f(Ah[(size_t)n * HC + t]) + bf2f(Al[(size_t)n * HC + t]);
    atomicAdd(p + t, acc);
}

// ---- K6: out[k] = b10[k] + (1/NN) * p512 . M[k,:] ; 10 waves ----
__global__ __launch_bounds__(640)
void final10(const float* __restrict__ p512, const float* __restrict__ M,
             const float* __restrict__ b10, float* __restrict__ out) {
    int k = threadIdx.x >> 6;
    int lane = threadIdx.x & 63;
    float acc = 0.f;
#pragma unroll
    for (int i = 0; i < HC / 64; ++i) {
        int j = lane + i * 64;
        acc += p512[j] * M[(size_t)k * HC + j];
    }
#pragma unroll
    for (int off = 32; off; off >>= 1) acc += __shfl_down(acc, off);
    if (lane == 0) out[k] = b10[k] + acc * (1.0f / NN);
}

extern "C" void kernel_launch(void* const* d_in, const int* in_sizes, int n_in,
                              void* d_out, int out_size, void* d_ws, size_t ws_size,
                              hipStream_t stream) {
    const int*   feats = (const int*)d_in[0];
    const int*   edges = (const int*)d_in[1];
    const float* emb   = (const float*)d_in[2];
    const float* W     = (const float*)d_in[3];
    const float* asrcW = (const float*)d_in[4];
    const float* adstW = (const float*)d_in[5];
    const float* bias  = (const float*)d_in[6];
    const float* Wc    = (const float*)d_in[7];
    const float* bc    = (const float*)d_in[8];
    float* out = (float*)d_out;

    const int* srcp = edges;
    const int* dstp = edges + NE;

    char* ws = (char*)d_ws;
    size_t off = 0;
    unsigned short* aggh = (unsigned short*)(ws + off); off += (size_t)NN * HC * 2;  // 10.24 MB
    unsigned short* aggl = (unsigned short*)(ws + off); off += (size_t)NN * HC * 2;  // 10.24 MB
    float* xb0    = (float*)(ws + off); off += (size_t)NN * D * 4;    // 5.12 MB
    float* xb1    = (float*)(ws + off); off += (size_t)NN * D * 4;    // 5.12 MB
    float* asrc   = (float*)(ws + off); off += (size_t)NN * NH * 4;
    float* adst   = (float*)(ws + off); off += (size_t)NN * NH * 4;
    int*   deg    = (int*)(ws + off);   off += (size_t)NN * 4;
    int*   rowst  = (int*)(ws + off);   off += (size_t)NN * 4;
    int*   cursor = (int*)(ws + off);   off += (size_t)NN * 4;
    int*   csrsrc = (int*)(ws + off);   off += (size_t)NE * 4;        // 0.64 MB
    float* wsrcb  = (float*)(ws + off); off += (size_t)NL * NH * D * 4;
    float* wdstb  = (float*)(ws + off); off += (size_t)NL * NH * D * 4;
    unsigned short* Bth = (unsigned short*)(ws + off); off += (size_t)2 * 128 * HC * 2; // 128 KB
    unsigned short* Btl = (unsigned short*)(ws + off); off += (size_t)2 * 128 * HC * 2;
    float* Mhead  = (float*)(ws + off); off += (size_t)NCLS * HC * 4; // 20 KB
    float* b10    = (float*)(ws + off); off += NCLS * 4;
    float* p512   = (float*)(ws + off); off += HC * 4;

    // ---- prep: CSR + merged weight-prep ----
    hipMemsetAsync(deg, 0, (size_t)NN * 4, stream);
    hist<<<(NE + 255) / 256, 256, 0, stream>>>(dstp, deg);
    scan_deg<<<1, SCAN_T, 0, stream>>>(deg, rowst, cursor);
    scatter<<<(NE + 255) / 256, 256, 0, stream>>>(srcp, dstp, cursor, csrsrc);
    prep_all<<<290, 512, 0, stream>>>(W, asrcW, adstW, Wc, bias, bc,
                                      wsrcb, wdstb, Bth, Btl, Mhead, b10, p512);

    // atom encoder with fused layer-0 alphas
    atom_encoder_alpha<<<NN, 128, 0, stream>>>(feats, emb, wsrcb, wdstb,
                                               xb0, asrc, adst);

    float* xin = xb0;
    float* xout = xb1;
    for (int l = 0; l < 2; ++l) {
        if (l > 0)
            alphas2<<<NN / 4, 256, 0, stream>>>(xin, wsrcb + (size_t)l * NH * D,
                                                wdstb + (size_t)l * NH * D, asrc, adst);
        gat_agg<<<NN, 128, 0, stream>>>(csrsrc, rowst, deg, asrc, adst, xin,
                                        (unsigned*)aggh, (unsigned*)aggl);
        gemm_mfma<<<dim3(NN / 16, 2), 64, 0, stream>>>(
            aggh, aggl, Bth + (size_t)l * 128 * HC, Btl + (size_t)l * 128 * HC,
            bias + (size_t)l * D, xout, 1);
        float* tmp = xin; xin = xout; xout = tmp;
    }

    // layer 3: attention+agg, then pool in agg-space (GEMM commuted past mean)
    alphas2<<<NN / 4, 256, 0, stream>>>(xin, wsrcb + (size_t)2 * NH * D,
                                        wdstb + (size_t)2 * NH * D, asrc, adst);
    gat_agg<<<NN, 128, 0, stream>>>(csrsrc, rowst, deg, asrc, adst, xin,
                                    (unsigned*)aggh, (unsigned*)aggl);
    pool512<<<100, 512, 0, stream>>>(aggh, aggl, p512);
    final10<<<1, 640, 0, stream>>>(p512, Mhead, b10, out);
}